// Round 15
// baseline (336.254 us; speedup 1.0000x reference)
//
#include <hip/hip_runtime.h>
#include <math.h>

#define NB   4
#define H1   1056
#define W1   1920
#define H2   528
#define W2   960
#define NBLK 220    // 11*20 blocks per image, both scales
#define NBW  20
#define NF   36
#define NGAM 9801
#define NSL1 4      // row-slices per 96-block
#define NCNT (NB * NBLK)                        // ticket counters (96-scale blocks)
#define NPART (NB * NBLK * NSL1 + NB * NBLK)    // 3520 + 880 = 4400

#define MS_BX (W1 / 32)            // 60
#define MS_BY (H1 / 32)            // 33
#define MS_NB (MS_BX * MS_BY * NB) // 7920
#define RS_BX (W2 / 32)            // 30
#define RS_BY ((H2 + 31) / 32)     // 17
#define RS_NB (RS_BX * RS_BY * NB) // 2040

__device__ __forceinline__ int reflect_idx(int i, int n) {
    if (i < 0) return -i - 1;
    if (i >= n) return 2 * n - i - 1;
    return i;
}

// ---------------- gray (float4 streaming) + tables + ticket-counter zeroing.
__global__ void k_gray_rgam(const float4* __restrict__ x, float4* __restrict__ y,
                            float* __restrict__ rg, float* __restrict__ rt,
                            float* __restrict__ mf, int* __restrict__ cnt) {
    const int W4 = W1 / 4;
    const int gtotal = NB * H1 * W4;
    int idx = blockIdx.x * 256 + threadIdx.x;
    if (idx < gtotal) {
        int w4 = idx % W4;
        int t  = idx / W4;
        int h  = t % H1;
        int b  = t / H1;
        size_t base = ((size_t)(b * 3) * 1080 + h) * W4 + w4;
        float4 r  = x[base];
        float4 g  = x[base + (size_t)1080 * W4];
        float4 bb = x[base + (size_t)2 * 1080 * W4];
        float4 o;
        o.x = rintf((0.299f * r.x + 0.587f * g.x + 0.114f * bb.x) * 255.0f);
        o.y = rintf((0.299f * r.y + 0.587f * g.y + 0.114f * bb.y) * 255.0f);
        o.z = rintf((0.299f * r.z + 0.587f * g.z + 0.114f * bb.z) * 255.0f);
        o.w = rintf((0.299f * r.w + 0.587f * g.w + 0.114f * bb.w) * 255.0f);
        y[idx] = o;
    } else {
        int i = idx - gtotal;
        if (i < NGAM) {
            float g = (float)i * 0.001f + 0.2f;
            float l1 = lgammaf(1.0f / g);
            float l2 = lgammaf(2.0f / g);
            float l3 = lgammaf(3.0f / g);
            rg[i] = expf(2.0f * l2 - l1 - l3);
            rt[i] = expf(0.5f * (l1 - l3));
            mf[i] = expf(l2 - l1);
        } else if (i < NGAM + NCNT) {
            cnt[i - NGAM] = 0;
        }
    }
}

// ---------------- MSCN body (register-blocked separable 7-tap) and resize body,
// shared-memory provided by caller so mscn1+resize can share one merged launch.
struct MscnS {
    float tile[38][40];
    float h1s[38][36];
    float h2s[38][36];
    float gw1[8];
};
struct ResizeS {
    float yt[70][72];
    float vv[32][72];
};

__device__ __forceinline__ void mscn_body(const float* __restrict__ src,
                                          float* __restrict__ out, int H, int W,
                                          int ox0, int oy0, int b,
                                          int tx, int ty, int tid, MscnS& S) {
    if (tid < 7) {
        double s = 7.0 / 6.0;
        double sum = 0.0;
        #pragma unroll
        for (int k = 0; k < 7; k++) sum += exp(-(double)((k - 3) * (k - 3)) / (2.0 * s * s));
        double e = exp(-(double)((tid - 3) * (tid - 3)) / (2.0 * s * s));
        S.gw1[tid] = (float)(e / sum);
    }

    const float* p = src + (size_t)b * H * W;
    for (int t = tid; t < 38 * 38; t += 256) {
        int r = t / 38, c = t % 38;
        int gr = oy0 - 3 + r; gr = gr < 0 ? 0 : (gr >= H ? H - 1 : gr);
        int gc = ox0 - 3 + c; gc = gc < 0 ? 0 : (gc >= W ? W - 1 : gc);
        S.tile[r][c] = p[(size_t)gr * W + gc];
    }
    __syncthreads();

    for (int t = tid; t < 38 * 8; t += 256) {
        int r = t / 8, c0 = (t % 8) * 4;
        float4 f0 = *(const float4*)&S.tile[r][c0];
        float4 f1 = *(const float4*)&S.tile[r][c0 + 4];
        float2 f2 = *(const float2*)&S.tile[r][c0 + 8];
        float v[10] = {f0.x, f0.y, f0.z, f0.w, f1.x, f1.y, f1.z, f1.w, f2.x, f2.y};
        float s1[4] = {0, 0, 0, 0}, s2[4] = {0, 0, 0, 0};
        #pragma unroll
        for (int k = 0; k < 7; k++) {
            float w = S.gw1[k];
            #pragma unroll
            for (int s = 0; s < 4; s++) {
                float vv = v[s + k];
                s1[s] += w * vv;
                s2[s] += w * vv * vv;
            }
        }
        *(float4*)&S.h1s[r][c0] = make_float4(s1[0], s1[1], s1[2], s1[3]);
        *(float4*)&S.h2s[r][c0] = make_float4(s2[0], s2[1], s2[2], s2[3]);
    }
    __syncthreads();

    int ly0 = ty * 4;
    float a1[10], a2[10];
    #pragma unroll
    for (int k = 0; k < 10; k++) { a1[k] = S.h1s[ly0 + k][tx]; a2[k] = S.h2s[ly0 + k][tx]; }
    float* q = out + (size_t)b * H * W;
    #pragma unroll
    for (int s = 0; s < 4; s++) {
        int oy = oy0 + ly0 + s, ox = ox0 + tx;
        if (oy < H) {
            float m1 = 0.0f, m2 = 0.0f;
            #pragma unroll
            for (int k = 0; k < 7; k++) {
                float w = S.gw1[k];
                m1 += w * a1[s + k];
                m2 += w * a2[s + k];
            }
            float sig = sqrtf(fabsf(m2 - m1 * m1));
            q[(size_t)oy * W + ox] = (S.tile[ly0 + s + 3][tx + 3] - m1) / (sig + 1.0f);
        }
    }
}

__device__ const float RW8[8] = {-0.01171875f, -0.03515625f, 0.11328125f, 0.43359375f,
                                  0.43359375f,  0.11328125f, -0.03515625f, -0.01171875f};

__device__ __forceinline__ void resize_body(const float* __restrict__ y,
                                            float* __restrict__ half,
                                            int j0, int i0, int b, int tid, ResizeS& S) {
    const float* py = y + (size_t)b * H1 * W1;
    int rbase = 2 * i0 - 3, cbase = 2 * j0 - 3;

    for (int t = tid; t < 70 * 70; t += 256) {
        int r = t / 70, c = t % 70;
        int gr = reflect_idx(rbase + r, H1);
        int gc = reflect_idx(cbase + c, W1);
        S.yt[r][c] = py[(size_t)gr * W1 + gc] / 255.0f;
    }
    __syncthreads();

    for (int t = tid; t < 32 * 70; t += 256) {
        int i = t / 70, c = t % 70;
        float acc = 0.0f;
        #pragma unroll
        for (int p = 0; p < 8; p++) acc += RW8[p] * S.yt[2 * i + p][c];
        S.vv[i][c] = acc;
    }
    __syncthreads();

    float* ph = half + (size_t)b * H2 * W2;
    for (int t = tid; t < 1024; t += 256) {
        int i = t >> 5, j = t & 31;
        int oy = i0 + i, ox = j0 + j;
        if (oy < H2 && ox < W2) {
            float acc = 0.0f;
            #pragma unroll
            for (int p = 0; p < 8; p++) acc += RW8[p] * S.vv[i][2 * j + p];
            ph[(size_t)oy * W2 + ox] = acc * 255.0f;
        }
    }
}

// merged mscn1 + resize (both consume y, independent of each other)
__global__ __launch_bounds__(256) void k_ms_rs(const float* __restrict__ y,
                                               float* __restrict__ nrm,
                                               float* __restrict__ half) {
    __shared__ __align__(16) char smem[sizeof(ResizeS)];   // 29376 > 17056
    int bid = blockIdx.x;
    int tid = threadIdx.x;
    int tx = tid & 31, ty = tid >> 5;
    if (bid < MS_NB) {
        int bx = bid % MS_BX;
        int t  = bid / MS_BX;
        int by = t % MS_BY;
        int b  = t / MS_BY;
        mscn_body(y, nrm, H1, W1, bx * 32, by * 32, b, tx, ty, tid,
                  *reinterpret_cast<MscnS*>(smem));
    } else {
        int rid = bid - MS_NB;
        int jx = rid % RS_BX;
        int t  = rid / RS_BX;
        int iy = t % RS_BY;
        int b  = t / RS_BY;
        resize_body(y, half, jx * 32, iy * 32, b, tid,
                    *reinterpret_cast<ResizeS*>(smem));
    }
}

// mscn2 (48-scale) standalone
__global__ __launch_bounds__(256) void k_mscn2(const float* __restrict__ src,
                                               float* __restrict__ out) {
    __shared__ MscnS S;
    int tid = threadIdx.x;
    mscn_body(src, out, H2, W2, blockIdx.x * 32, blockIdx.y * 32, blockIdx.z,
              tid & 31, tid >> 5, tid, S);
}

// ---------------- FEATS: per-slice partials + in-kernel ticket finalize.
template <int COLS, int TPR>
__device__ __forceinline__ void fpart_body(const float* __restrict__ p, int W,
                                           int row0, int BSfull,
                                           int tid, float wls[3][25]) {
    constexpr int SPAN = 12, CW = 4, NCH = 3;
    int lane = tid & 63, wv = tid >> 6;

    int li = tid / TPR;
    int c0 = (tid % TPR) * SPAN;
    int gi = row0 + li;
    int gim = (gi == 0) ? BSfull - 1 : gi - 1;
    const float* rowcp = p + (size_t)gi * W;
    const float* rowmp = p + (size_t)gim * W;

    float c2 = rowcp[c0 == 0 ? COLS - 1 : c0 - 1];
    float m2 = rowmp[c0 == 0 ? COLS - 1 : c0 - 1];
    float mrightE = rowmp[c0 + SPAN == COLS ? 0 : c0 + SPAN];

    float sn[5] = {0, 0, 0, 0, 0}, s2[5] = {0, 0, 0, 0, 0}, sa[5] = {0, 0, 0, 0, 0};
    int cneg[5] = {0, 0, 0, 0, 0}, cnz[5] = {0, 0, 0, 0, 0};

    auto PROC = [&](float v0, float cl, float up, float ul, float ur) {
        float v[5] = {v0, v0 * cl, v0 * up, v0 * ul, v0 * ur};
        #pragma unroll
        for (int s = 0; s < 5; s++) {
            float vv = v[s];
            float t = fminf(vv, 0.0f);
            sn[s] += t * t;
            s2[s] += vv * vv;
            sa[s] += fabsf(vv);
            cneg[s] += (int)__popcll(__ballot(vv < 0.0f));
            cnz[s]  += (int)__popcll(__ballot(vv != 0.0f));
        }
    };

    float c1 = 0.0f, m1 = 0.0f;
    #pragma unroll
    for (int j = 0; j < NCH; j++) {
        float cc[CW], mm[CW];
        {
            float4 v = *(const float4*)(rowcp + c0 + j * CW);
            cc[0] = v.x; cc[1] = v.y; cc[2] = v.z; cc[3] = v.w;
        }
        #pragma unroll
        for (int k = 0; k < CW; k++) mm[k] = __shfl_up(cc[k], TPR, 64);
        if (lane < TPR) {
            float4 v = *(const float4*)(rowmp + c0 + j * CW);
            mm[0] = v.x; mm[1] = v.y; mm[2] = v.z; mm[3] = v.w;
        }
        #pragma unroll
        for (int k = 0; k < CW; k++) {
            if (j == 0 && k == 0) { c1 = cc[0]; m1 = mm[0]; }
            else {
                PROC(c1, c2, m1, m2, mm[k]);
                c2 = c1; m2 = m1; c1 = cc[k]; m1 = mm[k];
            }
        }
    }
    PROC(c1, c2, m1, m2, mrightE);

    #pragma unroll
    for (int s = 0; s < 5; s++) {
        float vals[3] = {sn[s], s2[s], sa[s]};
        const int rows3[3] = {0, 1, 4};
        #pragma unroll
        for (int m = 0; m < 3; m++) {
            float v = vals[m];
            #pragma unroll
            for (int off = 32; off > 0; off >>= 1) v += __shfl_down(v, off, 64);
            if (lane == 0) wls[wv][s * 5 + rows3[m]] = v;
        }
        if (lane == 0) {
            wls[wv][s * 5 + 2] = (float)cneg[s];
            wls[wv][s * 5 + 3] = (float)cnz[s];
        }
    }
}

// finalize: ss[25] -> 18 features (tid<5 math, then wave-0 binary searches)
__device__ __forceinline__ void finalize_feats(int tid, int BS, const float* ss,
                                               float* srn, float* sls, float* srs,
                                               const float* __restrict__ rgam,
                                               const float* __restrict__ ratio_t,
                                               const float* __restrict__ meanfac_t,
                                               float* __restrict__ fp) {
    if (tid < 5) {
        int s = tid;
        float SN  = ss[s * 5 + 0];
        float S2  = ss[s * 5 + 1];
        float CN  = ss[s * 5 + 2];
        float CNZ = ss[s * 5 + 3];
        float SA  = ss[s * 5 + 4];
        float SP = S2 - SN;
        float CP = CNZ - CN;
        float ls = sqrtf(SN / CN);
        float rs = sqrtf(SP / CP);
        float gh = ls / rs;
        float Nn = (float)(BS * BS);
        float am = SA / Nn;
        float rhat = (am * am) / (S2 / Nn);
        float g2 = gh * gh;
        float rn = rhat * (g2 * gh + 1.0f) * (gh + 1.0f) / ((g2 + 1.0f) * (g2 + 1.0f));
        srn[s] = rn; sls[s] = ls; srs[s] = rs;
    }
    __syncthreads();
    if (tid < 64) {
        int lane = tid;
        for (int s = 0; s < 5; s++) {
            float rn = srn[s];
            int lo = -1, hi = NGAM;
            while (hi - lo > 1) {
                int n = hi - lo - 1;
                int stride = n / 65 + 1;
                int pi = lo + (lane + 1) * stride;
                bool valid = pi < hi;
                float v = valid ? rgam[pi] : 0.0f;
                unsigned long long blw = __ballot(valid && (v < rn));
                int k = __popcll(blw);
                int oldlo = lo;
                lo = oldlo + k * stride;
                int cand = oldlo + (k + 1) * stride;
                if (cand < hi) hi = cand;
            }
            int lb = hi;
            int ix;
            if (lb <= 0) ix = 0;
            else if (lb >= NGAM) ix = NGAM - 1;
            else {
                float dl = rgam[lb - 1] - rn, dr = rgam[lb] - rn;
                ix = (dl * dl <= dr * dr) ? lb - 1 : lb;
            }
            if (lane == 0) {
                float a = (float)ix * 0.001f + 0.2f;
                float ratio = ratio_t[ix];
                float bl = sls[s] * ratio;
                float br = srs[s] * ratio;
                if (s == 0) {
                    fp[0] = a; fp[1] = 0.5f * (bl + br);
                } else {
                    float mn = (br - bl) * meanfac_t[ix];
                    int base = 2 + (s - 1) * 4;
                    fp[base] = a; fp[base + 1] = mn; fp[base + 2] = bl; fp[base + 3] = br;
                }
            }
        }
    }
}

__global__ __launch_bounds__(192) void k_fpart(const float* __restrict__ nrm1,
                                               const float* __restrict__ nrm2,
                                               float* __restrict__ part,
                                               int* __restrict__ cnt,
                                               const float* __restrict__ rgam,
                                               const float* __restrict__ ratio_t,
                                               const float* __restrict__ meanfac_t,
                                               float* __restrict__ feats) {
    __shared__ float wls[3][25];
    __shared__ float ss[25];
    __shared__ float srn[5], sls[5], srs[5];
    __shared__ int dofin;
    int sg = blockIdx.x, tid = threadIdx.x;

    if (sg < NB * NBLK * NSL1) {
        int g = sg >> 2, sl = sg & 3;
        int b = g / NBLK, r = g % NBLK;
        const float* p = nrm1 + (size_t)b * H1 * W1 + (size_t)(r / NBW * 96) * W1
                       + (size_t)(r % NBW) * 96;
        fpart_body<96, 8>(p, W1, sl * 24, 96, tid, wls);
        __syncthreads();
        if (tid < 25) {
            atomicExch(&part[(size_t)sg * 25 + tid], wls[0][tid] + wls[1][tid] + wls[2][tid]);
            __threadfence();
        }
        __syncthreads();
        if (tid == 0) dofin = (atomicAdd(&cnt[g], 1) == NSL1 - 1) ? 1 : 0;
        __syncthreads();
        if (!dofin) return;
        __threadfence();
        if (tid < 25) {
            float s = 0.0f;
            #pragma unroll
            for (int sl2 = 0; sl2 < NSL1; sl2++)
                s += atomicAdd(&part[(size_t)(g * NSL1 + sl2) * 25 + tid], 0.0f);
            ss[tid] = s;
        }
        __syncthreads();
        finalize_feats(tid, 96, ss, srn, sls, srs, rgam, ratio_t, meanfac_t,
                       feats + (size_t)g * NF + 0);
    } else {
        int g = sg - NB * NBLK * NSL1;
        int b = g / NBLK, r = g % NBLK;
        const float* p = nrm2 + (size_t)b * H2 * W2 + (size_t)(r / NBW * 48) * W2
                       + (size_t)(r % NBW) * 48;
        fpart_body<48, 4>(p, W2, 0, 48, tid, wls);
        __syncthreads();
        if (tid < 25) ss[tid] = wls[0][tid] + wls[1][tid] + wls[2][tid];
        __syncthreads();
        finalize_feats(tid, 48, ss, srn, sls, srs, rgam, ratio_t, meanfac_t,
                       feats + (size_t)g * NF + 18);
    }
}

// ---------------- per-batch stats: cov via transposed dist + 3x3 register tiles,
// then no-pivot Gauss-Jordan (M is SPD), f32 throughout.
__global__ __launch_bounds__(256) void k_stats(const float* __restrict__ feats,
                                               const float* __restrict__ mu_pris,
                                               const float* __restrict__ cov_pris,
                                               float* __restrict__ out) {
    __shared__ float dist[NBLK * NF];
    __shared__ __align__(16) float distT[NF][228];
    __shared__ float mu[NF];
    __shared__ float M[NF][NF + 1];
    __shared__ float facs[NF];
    __shared__ float dd[NF];

    int b = blockIdx.x, tid = threadIdx.x;
    for (int t = tid; t < NBLK * NF; t += 256) dist[t] = feats[(size_t)b * NBLK * NF + t];
    __syncthreads();
    if (tid < NF) {
        float s = 0.0f;
        for (int n = 0; n < NBLK; n++) s += dist[n * NF + tid];
        mu[tid] = s / (float)NBLK;
    }
    __syncthreads();
    for (int t = tid; t < NF * NBLK; t += 256) {
        int f = t / NBLK, n = t % NBLK;
        distT[f][n] = dist[n * NF + f] - mu[f];
    }
    __syncthreads();

    if (tid < 144) {
        int f0 = (tid / 12) * 3, g0 = (tid % 12) * 3;
        float acc[3][3] = {{0,0,0},{0,0,0},{0,0,0}};
        for (int n = 0; n < NBLK; n += 4) {
            float4 A[3], B[3];
            #pragma unroll
            for (int i = 0; i < 3; i++) A[i] = *(const float4*)&distT[f0 + i][n];
            #pragma unroll
            for (int j = 0; j < 3; j++) B[j] = *(const float4*)&distT[g0 + j][n];
            #pragma unroll
            for (int i = 0; i < 3; i++)
                #pragma unroll
                for (int j = 0; j < 3; j++)
                    acc[i][j] += A[i].x * B[j].x + A[i].y * B[j].y
                               + A[i].z * B[j].z + A[i].w * B[j].w;
        }
        const float* cp = cov_pris + (size_t)b * NF * NF;
        #pragma unroll
        for (int i = 0; i < 3; i++)
            #pragma unroll
            for (int j = 0; j < 3; j++) {
                int f = f0 + i, gg = g0 + j;
                M[f][gg] = (cp[f * NF + gg] + acc[i][j] / (float)(NBLK - 1)) * 0.5f;
            }
    }
    if (tid < NF) {
        float d = mu_pris[b * NF + tid] - mu[tid];
        dd[tid] = d;
        M[tid][NF] = d;
    }
    __syncthreads();

    for (int k = 0; k < NF; k++) {
        if (tid < NF && tid != k) facs[tid] = M[tid][k] / M[k][k];
        __syncthreads();
        for (int t = tid; t < NF * (NF + 1); t += 256) {
            int i = t / (NF + 1), j = t % (NF + 1);
            if (i != k && j > k) M[i][j] -= facs[i] * M[k][j];
        }
        __syncthreads();
    }

    if (tid < 64) {
        double c = (tid < NF) ? (double)dd[tid] * ((double)M[tid][NF] / (double)M[tid][tid]) : 0.0;
        #pragma unroll
        for (int off = 32; off > 0; off >>= 1) c += __shfl_down(c, off, 64);
        if (tid == 0) out[b] = (float)sqrt(c);
    }
}

extern "C" void kernel_launch(void* const* d_in, const int* in_sizes, int n_in,
                              void* d_out, int out_size, void* d_ws, size_t ws_size,
                              hipStream_t stream) {
    const float* x        = (const float*)d_in[0];
    const float* mu_pris  = (const float*)d_in[1];
    const float* cov_pris = (const float*)d_in[2];
    float* out = (float*)d_out;
    float* ws  = (float*)d_ws;

    float* y     = ws;                          // NB*H1*W1 = 8,110,080
    float* nrm   = y + (size_t)NB * H1 * W1;    // 8,110,080
    float* half  = nrm + (size_t)NB * H1 * W1;  // 2,027,520
    float* nrm2  = half + (size_t)NB * H2 * W2; // 2,027,520
    float* rgam  = nrm2 + (size_t)NB * H2 * W2; // 9801
    float* ratio = rgam + NGAM;                 // 9801
    float* mfac  = ratio + NGAM;                // 9801
    float* feats = mfac + NGAM;                 // NB*220*36 = 31,680
    float* part  = feats + (size_t)NB * NBLK * NF;  // 4400*25 = 110,000
    int*   cnt   = (int*)(part + (size_t)NPART * 25);  // 880

    const int NGB = NB * H1 * (W1 / 4);         // gray items
    k_gray_rgam<<<(NGB + NGAM + NCNT + 255) / 256, 256, 0, stream>>>(
        (const float4*)x, (float4*)y, rgam, ratio, mfac, cnt);

    k_ms_rs<<<MS_NB + RS_NB, 256, 0, stream>>>(y, nrm, half);

    k_mscn2<<<dim3(RS_BX, RS_BY, NB), 256, 0, stream>>>(half, nrm2);

    k_fpart<<<NPART, 192, 0, stream>>>(nrm, nrm2, part, cnt, rgam, ratio, mfac, feats);

    k_stats<<<NB, 256, 0, stream>>>(feats, mu_pris, cov_pris, out);
}

// Round 16
// 163.272 us; speedup vs baseline: 2.0595x; 2.0595x over previous
//
#include <hip/hip_runtime.h>
#include <math.h>

#define NB   4
#define H1   1056
#define W1   1920
#define H2   528
#define W2   960
#define NBLK 220    // 11*20 blocks per image, both scales
#define NBW  20
#define NF   36
#define NGAM 9801
#define NSL1 4      // row-slices per 96-block
#define NPART (NB * NBLK * NSL1 + NB * NBLK)    // 3520 + 880 = 4400

#define MS_BX (W1 / 32)            // 60
#define MS_BY (H1 / 32)            // 33
#define MS_NB (MS_BX * MS_BY * NB) // 7920
#define RS_BX (W2 / 32)            // 30
#define RS_BY ((H2 + 31) / 32)     // 17
#define RS_NB (RS_BX * RS_BY * NB) // 2040

__device__ __forceinline__ int reflect_idx(int i, int n) {
    if (i < 0) return -i - 1;
    if (i >= n) return 2 * n - i - 1;
    return i;
}

// ---------------- gray (float4 streaming) + R_GAM/ratio/meanfac tables in one launch.
__global__ void k_gray_rgam(const float4* __restrict__ x, float4* __restrict__ y,
                            float* __restrict__ rg, float* __restrict__ rt,
                            float* __restrict__ mf) {
    const int W4 = W1 / 4;
    const int gtotal = NB * H1 * W4;
    int idx = blockIdx.x * 256 + threadIdx.x;
    if (idx < gtotal) {
        int w4 = idx % W4;
        int t  = idx / W4;
        int h  = t % H1;
        int b  = t / H1;
        size_t base = ((size_t)(b * 3) * 1080 + h) * W4 + w4;
        float4 r  = x[base];
        float4 g  = x[base + (size_t)1080 * W4];
        float4 bb = x[base + (size_t)2 * 1080 * W4];
        float4 o;
        o.x = rintf((0.299f * r.x + 0.587f * g.x + 0.114f * bb.x) * 255.0f);
        o.y = rintf((0.299f * r.y + 0.587f * g.y + 0.114f * bb.y) * 255.0f);
        o.z = rintf((0.299f * r.z + 0.587f * g.z + 0.114f * bb.z) * 255.0f);
        o.w = rintf((0.299f * r.w + 0.587f * g.w + 0.114f * bb.w) * 255.0f);
        y[idx] = o;
    } else {
        int i = idx - gtotal;
        if (i < NGAM) {
            float g = (float)i * 0.001f + 0.2f;
            float l1 = lgammaf(1.0f / g);
            float l2 = lgammaf(2.0f / g);
            float l3 = lgammaf(3.0f / g);
            rg[i] = expf(2.0f * l2 - l1 - l3);
            rt[i] = expf(0.5f * (l1 - l3));
            mf[i] = expf(l2 - l1);
        }
    }
}

// ---------------- MSCN body (register-blocked separable 7-tap) and resize body,
// shared-memory provided by caller so mscn1+resize can share one merged launch.
struct MscnS {
    float tile[38][40];
    float h1s[38][36];
    float h2s[38][36];
    float gw1[8];
};
struct ResizeS {
    float yt[70][72];
    float vv[32][72];
};

__device__ __forceinline__ void mscn_body(const float* __restrict__ src,
                                          float* __restrict__ out, int H, int W,
                                          int ox0, int oy0, int b,
                                          int tx, int ty, int tid, MscnS& S) {
    if (tid < 7) {
        double s = 7.0 / 6.0;
        double sum = 0.0;
        #pragma unroll
        for (int k = 0; k < 7; k++) sum += exp(-(double)((k - 3) * (k - 3)) / (2.0 * s * s));
        double e = exp(-(double)((tid - 3) * (tid - 3)) / (2.0 * s * s));
        S.gw1[tid] = (float)(e / sum);
    }

    const float* p = src + (size_t)b * H * W;
    for (int t = tid; t < 38 * 38; t += 256) {
        int r = t / 38, c = t % 38;
        int gr = oy0 - 3 + r; gr = gr < 0 ? 0 : (gr >= H ? H - 1 : gr);
        int gc = ox0 - 3 + c; gc = gc < 0 ? 0 : (gc >= W ? W - 1 : gc);
        S.tile[r][c] = p[(size_t)gr * W + gc];
    }
    __syncthreads();

    for (int t = tid; t < 38 * 8; t += 256) {
        int r = t / 8, c0 = (t % 8) * 4;
        float4 f0 = *(const float4*)&S.tile[r][c0];
        float4 f1 = *(const float4*)&S.tile[r][c0 + 4];
        float2 f2 = *(const float2*)&S.tile[r][c0 + 8];
        float v[10] = {f0.x, f0.y, f0.z, f0.w, f1.x, f1.y, f1.z, f1.w, f2.x, f2.y};
        float s1[4] = {0, 0, 0, 0}, s2[4] = {0, 0, 0, 0};
        #pragma unroll
        for (int k = 0; k < 7; k++) {
            float w = S.gw1[k];
            #pragma unroll
            for (int s = 0; s < 4; s++) {
                float vv = v[s + k];
                s1[s] += w * vv;
                s2[s] += w * vv * vv;
            }
        }
        *(float4*)&S.h1s[r][c0] = make_float4(s1[0], s1[1], s1[2], s1[3]);
        *(float4*)&S.h2s[r][c0] = make_float4(s2[0], s2[1], s2[2], s2[3]);
    }
    __syncthreads();

    int ly0 = ty * 4;
    float a1[10], a2[10];
    #pragma unroll
    for (int k = 0; k < 10; k++) { a1[k] = S.h1s[ly0 + k][tx]; a2[k] = S.h2s[ly0 + k][tx]; }
    float* q = out + (size_t)b * H * W;
    #pragma unroll
    for (int s = 0; s < 4; s++) {
        int oy = oy0 + ly0 + s, ox = ox0 + tx;
        if (oy < H) {
            float m1 = 0.0f, m2 = 0.0f;
            #pragma unroll
            for (int k = 0; k < 7; k++) {
                float w = S.gw1[k];
                m1 += w * a1[s + k];
                m2 += w * a2[s + k];
            }
            float sig = sqrtf(fabsf(m2 - m1 * m1));
            q[(size_t)oy * W + ox] = (S.tile[ly0 + s + 3][tx + 3] - m1) / (sig + 1.0f);
        }
    }
}

__device__ const float RW8[8] = {-0.01171875f, -0.03515625f, 0.11328125f, 0.43359375f,
                                  0.43359375f,  0.11328125f, -0.03515625f, -0.01171875f};

__device__ __forceinline__ void resize_body(const float* __restrict__ y,
                                            float* __restrict__ half,
                                            int j0, int i0, int b, int tid, ResizeS& S) {
    const float* py = y + (size_t)b * H1 * W1;
    int rbase = 2 * i0 - 3, cbase = 2 * j0 - 3;

    for (int t = tid; t < 70 * 70; t += 256) {
        int r = t / 70, c = t % 70;
        int gr = reflect_idx(rbase + r, H1);
        int gc = reflect_idx(cbase + c, W1);
        S.yt[r][c] = py[(size_t)gr * W1 + gc] / 255.0f;
    }
    __syncthreads();

    for (int t = tid; t < 32 * 70; t += 256) {
        int i = t / 70, c = t % 70;
        float acc = 0.0f;
        #pragma unroll
        for (int p = 0; p < 8; p++) acc += RW8[p] * S.yt[2 * i + p][c];
        S.vv[i][c] = acc;
    }
    __syncthreads();

    float* ph = half + (size_t)b * H2 * W2;
    for (int t = tid; t < 1024; t += 256) {
        int i = t >> 5, j = t & 31;
        int oy = i0 + i, ox = j0 + j;
        if (oy < H2 && ox < W2) {
            float acc = 0.0f;
            #pragma unroll
            for (int p = 0; p < 8; p++) acc += RW8[p] * S.vv[i][2 * j + p];
            ph[(size_t)oy * W2 + ox] = acc * 255.0f;
        }
    }
}

// merged mscn1 + resize (both consume y, independent of each other)
__global__ __launch_bounds__(256) void k_ms_rs(const float* __restrict__ y,
                                               float* __restrict__ nrm,
                                               float* __restrict__ half) {
    __shared__ __align__(16) char smem[sizeof(ResizeS)];   // 29376 > 17056
    int bid = blockIdx.x;
    int tid = threadIdx.x;
    int tx = tid & 31, ty = tid >> 5;
    if (bid < MS_NB) {
        int bx = bid % MS_BX;
        int t  = bid / MS_BX;
        int by = t % MS_BY;
        int b  = t / MS_BY;
        mscn_body(y, nrm, H1, W1, bx * 32, by * 32, b, tx, ty, tid,
                  *reinterpret_cast<MscnS*>(smem));
    } else {
        int rid = bid - MS_NB;
        int jx = rid % RS_BX;
        int t  = rid / RS_BX;
        int iy = t % RS_BY;
        int b  = t / RS_BY;
        resize_body(y, half, jx * 32, iy * 32, b, tid,
                    *reinterpret_cast<ResizeS*>(smem));
    }
}

// mscn2 (48-scale) standalone
__global__ __launch_bounds__(256) void k_mscn2(const float* __restrict__ src,
                                               float* __restrict__ out) {
    __shared__ MscnS S;
    int tid = threadIdx.x;
    mscn_body(src, out, H2, W2, blockIdx.x * 32, blockIdx.y * 32, blockIdx.z,
              tid & 31, tid >> 5, tid, S);
}

// ---------------- FEATS phase A: per-slice partial stats (plain stores, no atomics).
template <int COLS, int TPR>
__device__ __forceinline__ void fpart_body(const float* __restrict__ p, int W,
                                           int row0, int BSfull,
                                           float* __restrict__ outp) {
    constexpr int SPAN = 12, CW = 4, NCH = 3;
    __shared__ float wls[3][25];
    int tid = threadIdx.x, lane = tid & 63, wv = tid >> 6;

    int li = tid / TPR;
    int c0 = (tid % TPR) * SPAN;
    int gi = row0 + li;
    int gim = (gi == 0) ? BSfull - 1 : gi - 1;
    const float* rowcp = p + (size_t)gi * W;
    const float* rowmp = p + (size_t)gim * W;

    float c2 = rowcp[c0 == 0 ? COLS - 1 : c0 - 1];
    float m2 = rowmp[c0 == 0 ? COLS - 1 : c0 - 1];
    float mrightE = rowmp[c0 + SPAN == COLS ? 0 : c0 + SPAN];

    float sn[5] = {0, 0, 0, 0, 0}, s2[5] = {0, 0, 0, 0, 0}, sa[5] = {0, 0, 0, 0, 0};
    int cneg[5] = {0, 0, 0, 0, 0}, cnz[5] = {0, 0, 0, 0, 0};

    auto PROC = [&](float v0, float cl, float up, float ul, float ur) {
        float v[5] = {v0, v0 * cl, v0 * up, v0 * ul, v0 * ur};
        #pragma unroll
        for (int s = 0; s < 5; s++) {
            float vv = v[s];
            float t = fminf(vv, 0.0f);
            sn[s] += t * t;
            s2[s] += vv * vv;
            sa[s] += fabsf(vv);
            cneg[s] += (int)__popcll(__ballot(vv < 0.0f));
            cnz[s]  += (int)__popcll(__ballot(vv != 0.0f));
        }
    };

    float c1 = 0.0f, m1 = 0.0f;
    #pragma unroll
    for (int j = 0; j < NCH; j++) {
        float cc[CW], mm[CW];
        {
            float4 v = *(const float4*)(rowcp + c0 + j * CW);
            cc[0] = v.x; cc[1] = v.y; cc[2] = v.z; cc[3] = v.w;
        }
        #pragma unroll
        for (int k = 0; k < CW; k++) mm[k] = __shfl_up(cc[k], TPR, 64);
        if (lane < TPR) {
            float4 v = *(const float4*)(rowmp + c0 + j * CW);
            mm[0] = v.x; mm[1] = v.y; mm[2] = v.z; mm[3] = v.w;
        }
        #pragma unroll
        for (int k = 0; k < CW; k++) {
            if (j == 0 && k == 0) { c1 = cc[0]; m1 = mm[0]; }
            else {
                PROC(c1, c2, m1, m2, mm[k]);
                c2 = c1; m2 = m1; c1 = cc[k]; m1 = mm[k];
            }
        }
    }
    PROC(c1, c2, m1, m2, mrightE);

    #pragma unroll
    for (int s = 0; s < 5; s++) {
        float vals[3] = {sn[s], s2[s], sa[s]};
        const int rows3[3] = {0, 1, 4};
        #pragma unroll
        for (int m = 0; m < 3; m++) {
            float v = vals[m];
            #pragma unroll
            for (int off = 32; off > 0; off >>= 1) v += __shfl_down(v, off, 64);
            if (lane == 0) wls[wv][s * 5 + rows3[m]] = v;
        }
        if (lane == 0) {
            wls[wv][s * 5 + 2] = (float)cneg[s];
            wls[wv][s * 5 + 3] = (float)cnz[s];
        }
    }
    __syncthreads();
    if (tid < 25) outp[tid] = wls[0][tid] + wls[1][tid] + wls[2][tid];
}

__global__ __launch_bounds__(192) void k_fpart(const float* __restrict__ nrm1,
                                               const float* __restrict__ nrm2,
                                               float* __restrict__ part) {
    int sg = blockIdx.x;
    if (sg < NB * NBLK * NSL1) {
        int g = sg >> 2, sl = sg & 3;
        int b = g / NBLK, r = g % NBLK;
        const float* p = nrm1 + (size_t)b * H1 * W1 + (size_t)(r / NBW * 96) * W1
                       + (size_t)(r % NBW) * 96;
        fpart_body<96, 8>(p, W1, sl * 24, 96, part + (size_t)sg * 25);
    } else {
        int g = sg - NB * NBLK * NSL1;
        int b = g / NBLK, r = g % NBLK;
        const float* p = nrm2 + (size_t)b * H2 * W2 + (size_t)(r / NBW * 48) * W2
                       + (size_t)(r % NBW) * 48;
        fpart_body<48, 4>(p, W2, 0, 48, part + (size_t)sg * 25);
    }
}

// ---------------- FEATS phase B: combine partials, finalize, monotone binary search.
__global__ __launch_bounds__(64) void k_ffinal(const float* __restrict__ part,
                                               const float* __restrict__ rgam,
                                               const float* __restrict__ ratio_t,
                                               const float* __restrict__ meanfac_t,
                                               float* __restrict__ feats) {
    __shared__ float ss[25];
    __shared__ float srn[5], sls[5], srs[5];
    int g = blockIdx.x, lane = threadIdx.x;
    int FOFF, BS;
    if (g < NB * NBLK) {
        if (lane < 25) {
            float s = 0.0f;
            #pragma unroll
            for (int sl = 0; sl < NSL1; sl++)
                s += part[(size_t)(g * NSL1 + sl) * 25 + lane];
            ss[lane] = s;
        }
        FOFF = 0; BS = 96;
    } else {
        if (lane < 25) ss[lane] = part[(size_t)(NB * NBLK * NSL1 + (g - NB * NBLK)) * 25 + lane];
        FOFF = 18; BS = 48;
    }
    __syncthreads();

    if (lane < 5) {
        int s = lane;
        float SN  = ss[s * 5 + 0];
        float S2  = ss[s * 5 + 1];
        float CN  = ss[s * 5 + 2];
        float CNZ = ss[s * 5 + 3];
        float SA  = ss[s * 5 + 4];
        float SP = S2 - SN;
        float CP = CNZ - CN;
        float ls = sqrtf(SN / CN);
        float rs = sqrtf(SP / CP);
        float gh = ls / rs;
        float Nn = (float)(BS * BS);
        float am = SA / Nn;
        float rhat = (am * am) / (S2 / Nn);
        float g2 = gh * gh;
        float rn = rhat * (g2 * gh + 1.0f) * (gh + 1.0f) / ((g2 + 1.0f) * (g2 + 1.0f));
        srn[s] = rn; sls[s] = ls; srs[s] = rs;
    }
    __syncthreads();

    int gl = (g < NB * NBLK) ? g : g - NB * NBLK;
    float* fp = feats + (size_t)gl * NF + FOFF;
    for (int s = 0; s < 5; s++) {
        float rn = srn[s];
        int lo = -1, hi = NGAM;
        while (hi - lo > 1) {
            int n = hi - lo - 1;
            int stride = n / 65 + 1;
            int pi = lo + (lane + 1) * stride;
            bool valid = pi < hi;
            float v = valid ? rgam[pi] : 0.0f;
            unsigned long long blw = __ballot(valid && (v < rn));
            int k = __popcll(blw);
            int oldlo = lo;
            lo = oldlo + k * stride;
            int cand = oldlo + (k + 1) * stride;
            if (cand < hi) hi = cand;
        }
        int lb = hi;
        int ix;
        if (lb <= 0) ix = 0;
        else if (lb >= NGAM) ix = NGAM - 1;
        else {
            float dl = rgam[lb - 1] - rn, dr = rgam[lb] - rn;
            ix = (dl * dl <= dr * dr) ? lb - 1 : lb;
        }
        if (lane == 0) {
            float a = (float)ix * 0.001f + 0.2f;
            float ratio = ratio_t[ix];
            float bl = sls[s] * ratio;
            float br = srs[s] * ratio;
            if (s == 0) {
                fp[0] = a; fp[1] = 0.5f * (bl + br);
            } else {
                float mn = (br - bl) * meanfac_t[ix];
                int base = 2 + (s - 1) * 4;
                fp[base] = a; fp[base + 1] = mn; fp[base + 2] = bl; fp[base + 3] = br;
            }
        }
    }
}

// ---------------- per-batch stats: cov via transposed dist + 3x3 register tiles,
// then no-pivot Gauss-Jordan (M is SPD), f32 throughout.
__global__ __launch_bounds__(256) void k_stats(const float* __restrict__ feats,
                                               const float* __restrict__ mu_pris,
                                               const float* __restrict__ cov_pris,
                                               float* __restrict__ out) {
    __shared__ float dist[NBLK * NF];
    __shared__ __align__(16) float distT[NF][228];
    __shared__ float mu[NF];
    __shared__ float M[NF][NF + 1];
    __shared__ float facs[NF];
    __shared__ float dd[NF];

    int b = blockIdx.x, tid = threadIdx.x;
    for (int t = tid; t < NBLK * NF; t += 256) dist[t] = feats[(size_t)b * NBLK * NF + t];
    __syncthreads();
    if (tid < NF) {
        float s = 0.0f;
        for (int n = 0; n < NBLK; n++) s += dist[n * NF + tid];
        mu[tid] = s / (float)NBLK;
    }
    __syncthreads();
    for (int t = tid; t < NF * NBLK; t += 256) {
        int f = t / NBLK, n = t % NBLK;
        distT[f][n] = dist[n * NF + f] - mu[f];
    }
    __syncthreads();

    if (tid < 144) {
        int f0 = (tid / 12) * 3, g0 = (tid % 12) * 3;
        float acc[3][3] = {{0,0,0},{0,0,0},{0,0,0}};
        for (int n = 0; n < NBLK; n += 4) {
            float4 A[3], B[3];
            #pragma unroll
            for (int i = 0; i < 3; i++) A[i] = *(const float4*)&distT[f0 + i][n];
            #pragma unroll
            for (int j = 0; j < 3; j++) B[j] = *(const float4*)&distT[g0 + j][n];
            #pragma unroll
            for (int i = 0; i < 3; i++)
                #pragma unroll
                for (int j = 0; j < 3; j++)
                    acc[i][j] += A[i].x * B[j].x + A[i].y * B[j].y
                               + A[i].z * B[j].z + A[i].w * B[j].w;
        }
        const float* cp = cov_pris + (size_t)b * NF * NF;
        #pragma unroll
        for (int i = 0; i < 3; i++)
            #pragma unroll
            for (int j = 0; j < 3; j++) {
                int f = f0 + i, gg = g0 + j;
                M[f][gg] = (cp[f * NF + gg] + acc[i][j] / (float)(NBLK - 1)) * 0.5f;
            }
    }
    if (tid < NF) {
        float d = mu_pris[b * NF + tid] - mu[tid];
        dd[tid] = d;
        M[tid][NF] = d;
    }
    __syncthreads();

    for (int k = 0; k < NF; k++) {
        if (tid < NF && tid != k) facs[tid] = M[tid][k] / M[k][k];
        __syncthreads();
        for (int t = tid; t < NF * (NF + 1); t += 256) {
            int i = t / (NF + 1), j = t % (NF + 1);
            if (i != k && j > k) M[i][j] -= facs[i] * M[k][j];
        }
        __syncthreads();
    }

    if (tid < 64) {
        double c = (tid < NF) ? (double)dd[tid] * ((double)M[tid][NF] / (double)M[tid][tid]) : 0.0;
        #pragma unroll
        for (int off = 32; off > 0; off >>= 1) c += __shfl_down(c, off, 64);
        if (tid == 0) out[b] = (float)sqrt(c);
    }
}

extern "C" void kernel_launch(void* const* d_in, const int* in_sizes, int n_in,
                              void* d_out, int out_size, void* d_ws, size_t ws_size,
                              hipStream_t stream) {
    const float* x        = (const float*)d_in[0];
    const float* mu_pris  = (const float*)d_in[1];
    const float* cov_pris = (const float*)d_in[2];
    float* out = (float*)d_out;
    float* ws  = (float*)d_ws;

    float* y     = ws;                          // NB*H1*W1 = 8,110,080
    float* nrm   = y + (size_t)NB * H1 * W1;    // 8,110,080
    float* half  = nrm + (size_t)NB * H1 * W1;  // 2,027,520
    float* nrm2  = half + (size_t)NB * H2 * W2; // 2,027,520
    float* rgam  = nrm2 + (size_t)NB * H2 * W2; // 9801
    float* ratio = rgam + NGAM;                 // 9801
    float* mfac  = ratio + NGAM;                // 9801
    float* feats = mfac + NGAM;                 // NB*220*36 = 31,680
    float* part  = feats + (size_t)NB * NBLK * NF;  // 4400*25 = 110,000

    const int NGB = NB * H1 * (W1 / 4);         // gray items
    k_gray_rgam<<<(NGB + NGAM + 255) / 256, 256, 0, stream>>>(
        (const float4*)x, (float4*)y, rgam, ratio, mfac);

    k_ms_rs<<<MS_NB + RS_NB, 256, 0, stream>>>(y, nrm, half);

    k_mscn2<<<dim3(RS_BX, RS_BY, NB), 256, 0, stream>>>(half, nrm2);

    k_fpart<<<NPART, 192, 0, stream>>>(nrm, nrm2, part);
    k_ffinal<<<2 * NB * NBLK, 64, 0, stream>>>(part, rgam, ratio, mfac, feats);

    k_stats<<<NB, 256, 0, stream>>>(feats, mu_pris, cov_pris, out);
}

// Round 17
// 158.402 us; speedup vs baseline: 2.1228x; 1.0307x over previous
//
#include <hip/hip_runtime.h>
#include <math.h>

#define NB   4
#define H1   1056
#define W1   1920
#define H2   528
#define W2   960
#define NBLK 220    // 11*20 blocks per image, both scales
#define NBW  20
#define NF   36
#define NGAM 9801
#define NSL1 4      // row-slices per 96-block
#define NPART1 (NB * NBLK * NSL1)               // 3520 scale-1 slice partials

#define MS_BX (W1 / 32)            // 60
#define MS_BY (H1 / 32)            // 33
#define MS_NB (MS_BX * MS_BY * NB) // 7920
#define RS_BX (W2 / 32)            // 30
#define RS_BY ((H2 + 31) / 32)     // 17
#define RS_NB (RS_BX * RS_BY * NB) // 2040

__device__ __forceinline__ int reflect_idx(int i, int n) {
    if (i < 0) return -i - 1;
    if (i >= n) return 2 * n - i - 1;
    return i;
}

// ---------------- gray (8 px/thread, uchar8 output) + R_GAM tables in one launch.
// y values are rintf() results in [0,255] -> uchar roundtrip is bitwise exact.
__global__ void k_gray_rgam(const float4* __restrict__ x, uint2* __restrict__ y8,
                            float* __restrict__ rg, float* __restrict__ rt,
                            float* __restrict__ mf) {
    const int W8 = W1 / 8;                 // 240
    const int W4 = W1 / 4;                 // 480
    const int gtotal = NB * H1 * W8;
    int idx = blockIdx.x * 256 + threadIdx.x;
    if (idx < gtotal) {
        int w8 = idx % W8;
        int t  = idx / W8;
        int h  = t % H1;
        int b  = t / H1;
        size_t base = ((size_t)(b * 3) * 1080 + h) * W4 + w8 * 2;
        float4 r0 = x[base],                     r1 = x[base + 1];
        float4 g0 = x[base + (size_t)1080 * W4], g1 = x[base + (size_t)1080 * W4 + 1];
        float4 b0 = x[base + 2 * (size_t)1080 * W4], b1 = x[base + 2 * (size_t)1080 * W4 + 1];
        unsigned int v0, v1;
        {
            unsigned int a = (unsigned int)rintf((0.299f * r0.x + 0.587f * g0.x + 0.114f * b0.x) * 255.0f);
            unsigned int b_ = (unsigned int)rintf((0.299f * r0.y + 0.587f * g0.y + 0.114f * b0.y) * 255.0f);
            unsigned int c = (unsigned int)rintf((0.299f * r0.z + 0.587f * g0.z + 0.114f * b0.z) * 255.0f);
            unsigned int d = (unsigned int)rintf((0.299f * r0.w + 0.587f * g0.w + 0.114f * b0.w) * 255.0f);
            v0 = a | (b_ << 8) | (c << 16) | (d << 24);
        }
        {
            unsigned int a = (unsigned int)rintf((0.299f * r1.x + 0.587f * g1.x + 0.114f * b1.x) * 255.0f);
            unsigned int b_ = (unsigned int)rintf((0.299f * r1.y + 0.587f * g1.y + 0.114f * b1.y) * 255.0f);
            unsigned int c = (unsigned int)rintf((0.299f * r1.z + 0.587f * g1.z + 0.114f * b1.z) * 255.0f);
            unsigned int d = (unsigned int)rintf((0.299f * r1.w + 0.587f * g1.w + 0.114f * b1.w) * 255.0f);
            v1 = a | (b_ << 8) | (c << 16) | (d << 24);
        }
        y8[idx] = make_uint2(v0, v1);
    } else {
        int i = idx - gtotal;
        if (i < NGAM) {
            float g = (float)i * 0.001f + 0.2f;
            float l1 = lgammaf(1.0f / g);
            float l2 = lgammaf(2.0f / g);
            float l3 = lgammaf(3.0f / g);
            rg[i] = expf(2.0f * l2 - l1 - l3);
            rt[i] = expf(0.5f * (l1 - l3));
            mf[i] = expf(l2 - l1);
        }
    }
}

// ---------------- MSCN body (register-blocked separable 7-tap), templated source type.
struct MscnS {
    float tile[38][40];
    float h1s[38][36];
    float h2s[38][36];
    float gw1[8];
};
struct ResizeS {
    float yt[70][72];
    float vv[32][72];
};

template <typename T>
__device__ __forceinline__ void mscn_body(const T* __restrict__ src,
                                          float* __restrict__ out, int H, int W,
                                          int ox0, int oy0, int b,
                                          int tx, int ty, int tid, MscnS& S) {
    if (tid < 7) {
        double s = 7.0 / 6.0;
        double sum = 0.0;
        #pragma unroll
        for (int k = 0; k < 7; k++) sum += exp(-(double)((k - 3) * (k - 3)) / (2.0 * s * s));
        double e = exp(-(double)((tid - 3) * (tid - 3)) / (2.0 * s * s));
        S.gw1[tid] = (float)(e / sum);
    }

    const T* p = src + (size_t)b * H * W;
    for (int t = tid; t < 38 * 38; t += 256) {
        int r = t / 38, c = t % 38;
        int gr = oy0 - 3 + r; gr = gr < 0 ? 0 : (gr >= H ? H - 1 : gr);
        int gc = ox0 - 3 + c; gc = gc < 0 ? 0 : (gc >= W ? W - 1 : gc);
        S.tile[r][c] = (float)p[(size_t)gr * W + gc];
    }
    __syncthreads();

    for (int t = tid; t < 38 * 8; t += 256) {
        int r = t / 8, c0 = (t % 8) * 4;
        float4 f0 = *(const float4*)&S.tile[r][c0];
        float4 f1 = *(const float4*)&S.tile[r][c0 + 4];
        float2 f2 = *(const float2*)&S.tile[r][c0 + 8];
        float v[10] = {f0.x, f0.y, f0.z, f0.w, f1.x, f1.y, f1.z, f1.w, f2.x, f2.y};
        float s1[4] = {0, 0, 0, 0}, s2[4] = {0, 0, 0, 0};
        #pragma unroll
        for (int k = 0; k < 7; k++) {
            float w = S.gw1[k];
            #pragma unroll
            for (int s = 0; s < 4; s++) {
                float vv = v[s + k];
                s1[s] += w * vv;
                s2[s] += w * vv * vv;
            }
        }
        *(float4*)&S.h1s[r][c0] = make_float4(s1[0], s1[1], s1[2], s1[3]);
        *(float4*)&S.h2s[r][c0] = make_float4(s2[0], s2[1], s2[2], s2[3]);
    }
    __syncthreads();

    int ly0 = ty * 4;
    float a1[10], a2[10];
    #pragma unroll
    for (int k = 0; k < 10; k++) { a1[k] = S.h1s[ly0 + k][tx]; a2[k] = S.h2s[ly0 + k][tx]; }
    float* q = out + (size_t)b * H * W;
    #pragma unroll
    for (int s = 0; s < 4; s++) {
        int oy = oy0 + ly0 + s, ox = ox0 + tx;
        if (oy < H) {
            float m1 = 0.0f, m2 = 0.0f;
            #pragma unroll
            for (int k = 0; k < 7; k++) {
                float w = S.gw1[k];
                m1 += w * a1[s + k];
                m2 += w * a2[s + k];
            }
            float sig = sqrtf(fabsf(m2 - m1 * m1));
            q[(size_t)oy * W + ox] = (S.tile[ly0 + s + 3][tx + 3] - m1) / (sig + 1.0f);
        }
    }
}

__device__ const float RW8[8] = {-0.01171875f, -0.03515625f, 0.11328125f, 0.43359375f,
                                  0.43359375f,  0.11328125f, -0.03515625f, -0.01171875f};

__device__ __forceinline__ void resize_body(const unsigned char* __restrict__ y,
                                            float* __restrict__ half,
                                            int j0, int i0, int b, int tid, ResizeS& S) {
    const unsigned char* py = y + (size_t)b * H1 * W1;
    int rbase = 2 * i0 - 3, cbase = 2 * j0 - 3;

    for (int t = tid; t < 70 * 70; t += 256) {
        int r = t / 70, c = t % 70;
        int gr = reflect_idx(rbase + r, H1);
        int gc = reflect_idx(cbase + c, W1);
        S.yt[r][c] = (float)py[(size_t)gr * W1 + gc] / 255.0f;
    }
    __syncthreads();

    for (int t = tid; t < 32 * 70; t += 256) {
        int i = t / 70, c = t % 70;
        float acc = 0.0f;
        #pragma unroll
        for (int p = 0; p < 8; p++) acc += RW8[p] * S.yt[2 * i + p][c];
        S.vv[i][c] = acc;
    }
    __syncthreads();

    float* ph = half + (size_t)b * H2 * W2;
    for (int t = tid; t < 1024; t += 256) {
        int i = t >> 5, j = t & 31;
        int oy = i0 + i, ox = j0 + j;
        if (oy < H2 && ox < W2) {
            float acc = 0.0f;
            #pragma unroll
            for (int p = 0; p < 8; p++) acc += RW8[p] * S.vv[i][2 * j + p];
            ph[(size_t)oy * W2 + ox] = acc * 255.0f;
        }
    }
}

// merged mscn1 + resize (both consume uchar y, independent of each other)
__global__ __launch_bounds__(256) void k_ms_rs(const unsigned char* __restrict__ y,
                                               float* __restrict__ nrm,
                                               float* __restrict__ half) {
    __shared__ __align__(16) char smem[sizeof(ResizeS)];   // 29376 > 17056
    int bid = blockIdx.x;
    int tid = threadIdx.x;
    int tx = tid & 31, ty = tid >> 5;
    if (bid < MS_NB) {
        int bx = bid % MS_BX;
        int t  = bid / MS_BX;
        int by = t % MS_BY;
        int b  = t / MS_BY;
        mscn_body<unsigned char>(y, nrm, H1, W1, bx * 32, by * 32, b, tx, ty, tid,
                                 *reinterpret_cast<MscnS*>(smem));
    } else {
        int rid = bid - MS_NB;
        int jx = rid % RS_BX;
        int t  = rid / RS_BX;
        int iy = t % RS_BY;
        int b  = t / RS_BY;
        resize_body(y, half, jx * 32, iy * 32, b, tid,
                    *reinterpret_cast<ResizeS*>(smem));
    }
}

// ---------------- FEATS phase A body: per-slice partial stats (first 192 threads work;
// callers may have 256 threads — extras just join the barrier).
template <int COLS, int TPR>
__device__ __forceinline__ void fpart_body(const float* __restrict__ p, int W,
                                           int row0, int BSfull, int tid,
                                           float* __restrict__ outp) {
    constexpr int SPAN = 12, CW = 4, NCH = 3;
    __shared__ float wls[3][25];
    if (tid < 192) {
        int lane = tid & 63, wv = tid >> 6;
        int li = tid / TPR;
        int c0 = (tid % TPR) * SPAN;
        int gi = row0 + li;
        int gim = (gi == 0) ? BSfull - 1 : gi - 1;
        const float* rowcp = p + (size_t)gi * W;
        const float* rowmp = p + (size_t)gim * W;

        float c2 = rowcp[c0 == 0 ? COLS - 1 : c0 - 1];
        float m2 = rowmp[c0 == 0 ? COLS - 1 : c0 - 1];
        float mrightE = rowmp[c0 + SPAN == COLS ? 0 : c0 + SPAN];

        float sn[5] = {0, 0, 0, 0, 0}, s2[5] = {0, 0, 0, 0, 0}, sa[5] = {0, 0, 0, 0, 0};
        int cneg[5] = {0, 0, 0, 0, 0}, cnz[5] = {0, 0, 0, 0, 0};

        auto PROC = [&](float v0, float cl, float up, float ul, float ur) {
            float v[5] = {v0, v0 * cl, v0 * up, v0 * ul, v0 * ur};
            #pragma unroll
            for (int s = 0; s < 5; s++) {
                float vv = v[s];
                float t = fminf(vv, 0.0f);
                sn[s] += t * t;
                s2[s] += vv * vv;
                sa[s] += fabsf(vv);
                cneg[s] += (int)__popcll(__ballot(vv < 0.0f));
                cnz[s]  += (int)__popcll(__ballot(vv != 0.0f));
            }
        };

        float c1 = 0.0f, m1 = 0.0f;
        #pragma unroll
        for (int j = 0; j < NCH; j++) {
            float cc[CW], mm[CW];
            {
                float4 v = *(const float4*)(rowcp + c0 + j * CW);
                cc[0] = v.x; cc[1] = v.y; cc[2] = v.z; cc[3] = v.w;
            }
            #pragma unroll
            for (int k = 0; k < CW; k++) mm[k] = __shfl_up(cc[k], TPR, 64);
            if (lane < TPR) {
                float4 v = *(const float4*)(rowmp + c0 + j * CW);
                mm[0] = v.x; mm[1] = v.y; mm[2] = v.z; mm[3] = v.w;
            }
            #pragma unroll
            for (int k = 0; k < CW; k++) {
                if (j == 0 && k == 0) { c1 = cc[0]; m1 = mm[0]; }
                else {
                    PROC(c1, c2, m1, m2, mm[k]);
                    c2 = c1; m2 = m1; c1 = cc[k]; m1 = mm[k];
                }
            }
        }
        PROC(c1, c2, m1, m2, mrightE);

        #pragma unroll
        for (int s = 0; s < 5; s++) {
            float vals[3] = {sn[s], s2[s], sa[s]};
            const int rows3[3] = {0, 1, 4};
            #pragma unroll
            for (int m = 0; m < 3; m++) {
                float v = vals[m];
                #pragma unroll
                for (int off = 32; off > 0; off >>= 1) v += __shfl_down(v, off, 64);
                if (lane == 0) wls[wv][s * 5 + rows3[m]] = v;
            }
            if (lane == 0) {
                wls[wv][s * 5 + 2] = (float)cneg[s];
                wls[wv][s * 5 + 3] = (float)cnz[s];
            }
        }
    }
    __syncthreads();
    if (tid < 25) outp[tid] = wls[0][tid] + wls[1][tid] + wls[2][tid];
}

// finalize: ss[25] -> 18 features
__device__ __forceinline__ void finalize_feats(int tid, int BS, const float* ss,
                                               float* srn, float* sls, float* srs,
                                               const float* __restrict__ rgam,
                                               const float* __restrict__ ratio_t,
                                               const float* __restrict__ meanfac_t,
                                               float* __restrict__ fp) {
    if (tid < 5) {
        int s = tid;
        float SN  = ss[s * 5 + 0];
        float S2  = ss[s * 5 + 1];
        float CN  = ss[s * 5 + 2];
        float CNZ = ss[s * 5 + 3];
        float SA  = ss[s * 5 + 4];
        float SP = S2 - SN;
        float CP = CNZ - CN;
        float ls = sqrtf(SN / CN);
        float rs = sqrtf(SP / CP);
        float gh = ls / rs;
        float Nn = (float)(BS * BS);
        float am = SA / Nn;
        float rhat = (am * am) / (S2 / Nn);
        float g2 = gh * gh;
        float rn = rhat * (g2 * gh + 1.0f) * (gh + 1.0f) / ((g2 + 1.0f) * (g2 + 1.0f));
        srn[s] = rn; sls[s] = ls; srs[s] = rs;
    }
    __syncthreads();
    if (tid < 64) {
        int lane = tid;
        for (int s = 0; s < 5; s++) {
            float rn = srn[s];
            int lo = -1, hi = NGAM;
            while (hi - lo > 1) {
                int n = hi - lo - 1;
                int stride = n / 65 + 1;
                int pi = lo + (lane + 1) * stride;
                bool valid = pi < hi;
                float v = valid ? rgam[pi] : 0.0f;
                unsigned long long blw = __ballot(valid && (v < rn));
                int k = __popcll(blw);
                int oldlo = lo;
                lo = oldlo + k * stride;
                int cand = oldlo + (k + 1) * stride;
                if (cand < hi) hi = cand;
            }
            int lb = hi;
            int ix;
            if (lb <= 0) ix = 0;
            else if (lb >= NGAM) ix = NGAM - 1;
            else {
                float dl = rgam[lb - 1] - rn, dr = rgam[lb] - rn;
                ix = (dl * dl <= dr * dr) ? lb - 1 : lb;
            }
            if (lane == 0) {
                float a = (float)ix * 0.001f + 0.2f;
                float ratio = ratio_t[ix];
                float bl = sls[s] * ratio;
                float br = srs[s] * ratio;
                if (s == 0) {
                    fp[0] = a; fp[1] = 0.5f * (bl + br);
                } else {
                    float mn = (br - bl) * meanfac_t[ix];
                    int base = 2 + (s - 1) * 4;
                    fp[base] = a; fp[base + 1] = mn; fp[base + 2] = bl; fp[base + 3] = br;
                }
            }
        }
    }
}

// ---------------- merged: fpart scale-1 (3520 blocks, long pole first) + mscn2 (2040)
__global__ __launch_bounds__(256) void k_mscn2_fpart1(const float* __restrict__ nrm,
                                                      const float* __restrict__ half,
                                                      float* __restrict__ nrm2,
                                                      float* __restrict__ part) {
    __shared__ __align__(16) char smem[sizeof(MscnS)];
    int bid = blockIdx.x, tid = threadIdx.x;
    if (bid < NPART1) {
        int g = bid >> 2, sl = bid & 3;
        int b = g / NBLK, r = g % NBLK;
        const float* p = nrm + (size_t)b * H1 * W1 + (size_t)(r / NBW * 96) * W1
                       + (size_t)(r % NBW) * 96;
        fpart_body<96, 8>(p, W1, sl * 24, 96, tid, part + (size_t)bid * 25);
    } else {
        int rid = bid - NPART1;
        int jx = rid % RS_BX;
        int t  = rid / RS_BX;
        int iy = t % RS_BY;
        int b  = t / RS_BY;
        mscn_body<float>(half, nrm2, H2, W2, jx * 32, iy * 32, b,
                         tid & 31, tid >> 5, tid, *reinterpret_cast<MscnS*>(smem));
    }
}

// ---------------- merged: fpart scale-2 with INTRA-BLOCK finalize (880) + ffinal scale-1 (880)
__global__ __launch_bounds__(192) void k_fpart2_ffinal1(const float* __restrict__ nrm2,
                                                        const float* __restrict__ part,
                                                        const float* __restrict__ rgam,
                                                        const float* __restrict__ ratio_t,
                                                        const float* __restrict__ meanfac_t,
                                                        float* __restrict__ feats) {
    __shared__ float ss[25];
    __shared__ float srn[5], sls[5], srs[5];
    int bid = blockIdx.x, tid = threadIdx.x;
    if (bid < NB * NBLK) {
        int g = bid;
        int b = g / NBLK, r = g % NBLK;
        const float* p = nrm2 + (size_t)b * H2 * W2 + (size_t)(r / NBW * 48) * W2
                       + (size_t)(r % NBW) * 48;
        fpart_body<48, 4>(p, W2, 0, 48, tid, ss);
        __syncthreads();
        finalize_feats(tid, 48, ss, srn, sls, srs, rgam, ratio_t, meanfac_t,
                       feats + (size_t)g * NF + 18);
    } else {
        int g = bid - NB * NBLK;
        if (tid < 25) {
            float s = 0.0f;
            #pragma unroll
            for (int sl = 0; sl < NSL1; sl++)
                s += part[(size_t)(g * NSL1 + sl) * 25 + tid];
            ss[tid] = s;
        }
        __syncthreads();
        finalize_feats(tid, 96, ss, srn, sls, srs, rgam, ratio_t, meanfac_t,
                       feats + (size_t)g * NF + 0);
    }
}

// ---------------- per-batch stats: cov via transposed dist + 3x3 register tiles,
// then no-pivot Gauss-Jordan (M is SPD), f32 throughout.
__global__ __launch_bounds__(256) void k_stats(const float* __restrict__ feats,
                                               const float* __restrict__ mu_pris,
                                               const float* __restrict__ cov_pris,
                                               float* __restrict__ out) {
    __shared__ float dist[NBLK * NF];
    __shared__ __align__(16) float distT[NF][228];
    __shared__ float mu[NF];
    __shared__ float M[NF][NF + 1];
    __shared__ float facs[NF];
    __shared__ float dd[NF];

    int b = blockIdx.x, tid = threadIdx.x;
    for (int t = tid; t < NBLK * NF; t += 256) dist[t] = feats[(size_t)b * NBLK * NF + t];
    __syncthreads();
    if (tid < NF) {
        float s = 0.0f;
        for (int n = 0; n < NBLK; n++) s += dist[n * NF + tid];
        mu[tid] = s / (float)NBLK;
    }
    __syncthreads();
    for (int t = tid; t < NF * NBLK; t += 256) {
        int f = t / NBLK, n = t % NBLK;
        distT[f][n] = dist[n * NF + f] - mu[f];
    }
    __syncthreads();

    if (tid < 144) {
        int f0 = (tid / 12) * 3, g0 = (tid % 12) * 3;
        float acc[3][3] = {{0,0,0},{0,0,0},{0,0,0}};
        for (int n = 0; n < NBLK; n += 4) {
            float4 A[3], B[3];
            #pragma unroll
            for (int i = 0; i < 3; i++) A[i] = *(const float4*)&distT[f0 + i][n];
            #pragma unroll
            for (int j = 0; j < 3; j++) B[j] = *(const float4*)&distT[g0 + j][n];
            #pragma unroll
            for (int i = 0; i < 3; i++)
                #pragma unroll
                for (int j = 0; j < 3; j++)
                    acc[i][j] += A[i].x * B[j].x + A[i].y * B[j].y
                               + A[i].z * B[j].z + A[i].w * B[j].w;
        }
        const float* cp = cov_pris + (size_t)b * NF * NF;
        #pragma unroll
        for (int i = 0; i < 3; i++)
            #pragma unroll
            for (int j = 0; j < 3; j++) {
                int f = f0 + i, gg = g0 + j;
                M[f][gg] = (cp[f * NF + gg] + acc[i][j] / (float)(NBLK - 1)) * 0.5f;
            }
    }
    if (tid < NF) {
        float d = mu_pris[b * NF + tid] - mu[tid];
        dd[tid] = d;
        M[tid][NF] = d;
    }
    __syncthreads();

    for (int k = 0; k < NF; k++) {
        if (tid < NF && tid != k) facs[tid] = M[tid][k] / M[k][k];
        __syncthreads();
        for (int t = tid; t < NF * (NF + 1); t += 256) {
            int i = t / (NF + 1), j = t % (NF + 1);
            if (i != k && j > k) M[i][j] -= facs[i] * M[k][j];
        }
        __syncthreads();
    }

    if (tid < 64) {
        double c = (tid < NF) ? (double)dd[tid] * ((double)M[tid][NF] / (double)M[tid][tid]) : 0.0;
        #pragma unroll
        for (int off = 32; off > 0; off >>= 1) c += __shfl_down(c, off, 64);
        if (tid == 0) out[b] = (float)sqrt(c);
    }
}

extern "C" void kernel_launch(void* const* d_in, const int* in_sizes, int n_in,
                              void* d_out, int out_size, void* d_ws, size_t ws_size,
                              hipStream_t stream) {
    const float* x        = (const float*)d_in[0];
    const float* mu_pris  = (const float*)d_in[1];
    const float* cov_pris = (const float*)d_in[2];
    float* out = (float*)d_out;
    float* ws  = (float*)d_ws;

    unsigned char* y8 = (unsigned char*)ws;               // NB*H1*W1 bytes
    float* nrm   = ws + (size_t)NB * H1 * W1 / 4;         // 8,110,080 floats
    float* half  = nrm + (size_t)NB * H1 * W1;            // 2,027,520
    float* nrm2  = half + (size_t)NB * H2 * W2;           // 2,027,520
    float* rgam  = nrm2 + (size_t)NB * H2 * W2;           // 9801
    float* ratio = rgam + NGAM;                           // 9801
    float* mfac  = ratio + NGAM;                          // 9801
    float* feats = mfac + NGAM;                           // NB*220*36 = 31,680
    float* part  = feats + (size_t)NB * NBLK * NF;        // 3520*25 = 88,000

    const int NGB8 = NB * H1 * (W1 / 8);
    k_gray_rgam<<<(NGB8 + NGAM + 255) / 256, 256, 0, stream>>>(
        (const float4*)x, (uint2*)y8, rgam, ratio, mfac);

    k_ms_rs<<<MS_NB + RS_NB, 256, 0, stream>>>(y8, nrm, half);

    k_mscn2_fpart1<<<NPART1 + RS_NB, 256, 0, stream>>>(nrm, half, nrm2, part);

    k_fpart2_ffinal1<<<2 * NB * NBLK, 192, 0, stream>>>(nrm2, part, rgam, ratio, mfac, feats);

    k_stats<<<NB, 256, 0, stream>>>(feats, mu_pris, cov_pris, out);
}

// Round 18
// 155.674 us; speedup vs baseline: 2.1600x; 1.0175x over previous
//
#include <hip/hip_runtime.h>
#include <math.h>

#define NB   4
#define H1   1056
#define W1   1920
#define H2   528
#define W2   960
#define NBLK 220    // 11*20 blocks per image, both scales
#define NBW  20
#define NF   36
#define NGAM 9801
#define NSL1 3      // row-slices per 96-block (32 rows each -> 256 threads exactly)
#define NPART1 (NB * NBLK * NSL1)               // 2640 scale-1 slice partials

#define MS_BX (W1 / 32)            // 60
#define MS_BY (H1 / 32)            // 33
#define MS_NB (MS_BX * MS_BY * NB) // 7920
#define RS_BX (W2 / 32)            // 30
#define RS_BY ((H2 + 31) / 32)     // 17
#define RS_NB (RS_BX * RS_BY * NB) // 2040

__device__ __forceinline__ int reflect_idx(int i, int n) {
    if (i < 0) return -i - 1;
    if (i >= n) return 2 * n - i - 1;
    return i;
}

// ---------------- gray (8 px/thread, uchar8 output) + R_GAM tables in one launch.
// y values are rintf() results in [0,255] -> uchar roundtrip is bitwise exact.
__global__ void k_gray_rgam(const float4* __restrict__ x, uint2* __restrict__ y8,
                            float* __restrict__ rg, float* __restrict__ rt,
                            float* __restrict__ mf) {
    const int W8 = W1 / 8;                 // 240
    const int W4 = W1 / 4;                 // 480
    const int gtotal = NB * H1 * W8;
    int idx = blockIdx.x * 256 + threadIdx.x;
    if (idx < gtotal) {
        int w8 = idx % W8;
        int t  = idx / W8;
        int h  = t % H1;
        int b  = t / H1;
        size_t base = ((size_t)(b * 3) * 1080 + h) * W4 + w8 * 2;
        float4 r0 = x[base],                     r1 = x[base + 1];
        float4 g0 = x[base + (size_t)1080 * W4], g1 = x[base + (size_t)1080 * W4 + 1];
        float4 b0 = x[base + 2 * (size_t)1080 * W4], b1 = x[base + 2 * (size_t)1080 * W4 + 1];
        unsigned int v0, v1;
        {
            unsigned int a = (unsigned int)rintf((0.299f * r0.x + 0.587f * g0.x + 0.114f * b0.x) * 255.0f);
            unsigned int b_ = (unsigned int)rintf((0.299f * r0.y + 0.587f * g0.y + 0.114f * b0.y) * 255.0f);
            unsigned int c = (unsigned int)rintf((0.299f * r0.z + 0.587f * g0.z + 0.114f * b0.z) * 255.0f);
            unsigned int d = (unsigned int)rintf((0.299f * r0.w + 0.587f * g0.w + 0.114f * b0.w) * 255.0f);
            v0 = a | (b_ << 8) | (c << 16) | (d << 24);
        }
        {
            unsigned int a = (unsigned int)rintf((0.299f * r1.x + 0.587f * g1.x + 0.114f * b1.x) * 255.0f);
            unsigned int b_ = (unsigned int)rintf((0.299f * r1.y + 0.587f * g1.y + 0.114f * b1.y) * 255.0f);
            unsigned int c = (unsigned int)rintf((0.299f * r1.z + 0.587f * g1.z + 0.114f * b1.z) * 255.0f);
            unsigned int d = (unsigned int)rintf((0.299f * r1.w + 0.587f * g1.w + 0.114f * b1.w) * 255.0f);
            v1 = a | (b_ << 8) | (c << 16) | (d << 24);
        }
        y8[idx] = make_uint2(v0, v1);
    } else {
        int i = idx - gtotal;
        if (i < NGAM) {
            float g = (float)i * 0.001f + 0.2f;
            float l1 = lgammaf(1.0f / g);
            float l2 = lgammaf(2.0f / g);
            float l3 = lgammaf(3.0f / g);
            rg[i] = expf(2.0f * l2 - l1 - l3);
            rt[i] = expf(0.5f * (l1 - l3));
            mf[i] = expf(l2 - l1);
        }
    }
}

// ---------------- MSCN body (register-blocked separable 7-tap), templated source type.
struct MscnS {
    float tile[38][40];
    float h1s[38][36];
    float h2s[38][36];
    float gw1[8];
};
struct ResizeS {
    float yt[70][72];
    float vv[32][72];
};

template <typename T>
__device__ __forceinline__ void mscn_body(const T* __restrict__ src,
                                          float* __restrict__ out, int H, int W,
                                          int ox0, int oy0, int b,
                                          int tx, int ty, int tid, MscnS& S) {
    if (tid < 7) {
        double s = 7.0 / 6.0;
        double sum = 0.0;
        #pragma unroll
        for (int k = 0; k < 7; k++) sum += exp(-(double)((k - 3) * (k - 3)) / (2.0 * s * s));
        double e = exp(-(double)((tid - 3) * (tid - 3)) / (2.0 * s * s));
        S.gw1[tid] = (float)(e / sum);
    }

    const T* p = src + (size_t)b * H * W;
    for (int t = tid; t < 38 * 38; t += 256) {
        int r = t / 38, c = t % 38;
        int gr = oy0 - 3 + r; gr = gr < 0 ? 0 : (gr >= H ? H - 1 : gr);
        int gc = ox0 - 3 + c; gc = gc < 0 ? 0 : (gc >= W ? W - 1 : gc);
        S.tile[r][c] = (float)p[(size_t)gr * W + gc];
    }
    __syncthreads();

    for (int t = tid; t < 38 * 8; t += 256) {
        int r = t / 8, c0 = (t % 8) * 4;
        float4 f0 = *(const float4*)&S.tile[r][c0];
        float4 f1 = *(const float4*)&S.tile[r][c0 + 4];
        float2 f2 = *(const float2*)&S.tile[r][c0 + 8];
        float v[10] = {f0.x, f0.y, f0.z, f0.w, f1.x, f1.y, f1.z, f1.w, f2.x, f2.y};
        float s1[4] = {0, 0, 0, 0}, s2[4] = {0, 0, 0, 0};
        #pragma unroll
        for (int k = 0; k < 7; k++) {
            float w = S.gw1[k];
            #pragma unroll
            for (int s = 0; s < 4; s++) {
                float vv = v[s + k];
                s1[s] += w * vv;
                s2[s] += w * vv * vv;
            }
        }
        *(float4*)&S.h1s[r][c0] = make_float4(s1[0], s1[1], s1[2], s1[3]);
        *(float4*)&S.h2s[r][c0] = make_float4(s2[0], s2[1], s2[2], s2[3]);
    }
    __syncthreads();

    int ly0 = ty * 4;
    float a1[10], a2[10];
    #pragma unroll
    for (int k = 0; k < 10; k++) { a1[k] = S.h1s[ly0 + k][tx]; a2[k] = S.h2s[ly0 + k][tx]; }
    float* q = out + (size_t)b * H * W;
    #pragma unroll
    for (int s = 0; s < 4; s++) {
        int oy = oy0 + ly0 + s, ox = ox0 + tx;
        if (oy < H) {
            float m1 = 0.0f, m2 = 0.0f;
            #pragma unroll
            for (int k = 0; k < 7; k++) {
                float w = S.gw1[k];
                m1 += w * a1[s + k];
                m2 += w * a2[s + k];
            }
            float sig = sqrtf(fabsf(m2 - m1 * m1));
            q[(size_t)oy * W + ox] = (S.tile[ly0 + s + 3][tx + 3] - m1) / (sig + 1.0f);
        }
    }
}

__device__ const float RW8[8] = {-0.01171875f, -0.03515625f, 0.11328125f, 0.43359375f,
                                  0.43359375f,  0.11328125f, -0.03515625f, -0.01171875f};

__device__ __forceinline__ void resize_body(const unsigned char* __restrict__ y,
                                            float* __restrict__ half,
                                            int j0, int i0, int b, int tid, ResizeS& S) {
    const unsigned char* py = y + (size_t)b * H1 * W1;
    int rbase = 2 * i0 - 3, cbase = 2 * j0 - 3;

    for (int t = tid; t < 70 * 70; t += 256) {
        int r = t / 70, c = t % 70;
        int gr = reflect_idx(rbase + r, H1);
        int gc = reflect_idx(cbase + c, W1);
        S.yt[r][c] = (float)py[(size_t)gr * W1 + gc] / 255.0f;
    }
    __syncthreads();

    for (int t = tid; t < 32 * 70; t += 256) {
        int i = t / 70, c = t % 70;
        float acc = 0.0f;
        #pragma unroll
        for (int p = 0; p < 8; p++) acc += RW8[p] * S.yt[2 * i + p][c];
        S.vv[i][c] = acc;
    }
    __syncthreads();

    float* ph = half + (size_t)b * H2 * W2;
    for (int t = tid; t < 1024; t += 256) {
        int i = t >> 5, j = t & 31;
        int oy = i0 + i, ox = j0 + j;
        if (oy < H2 && ox < W2) {
            float acc = 0.0f;
            #pragma unroll
            for (int p = 0; p < 8; p++) acc += RW8[p] * S.vv[i][2 * j + p];
            ph[(size_t)oy * W2 + ox] = acc * 255.0f;
        }
    }
}

// merged mscn1 + resize (both consume uchar y, independent of each other)
__global__ __launch_bounds__(256) void k_ms_rs(const unsigned char* __restrict__ y,
                                               float* __restrict__ nrm,
                                               float* __restrict__ half) {
    __shared__ __align__(16) char smem[sizeof(ResizeS)];   // 29376 > 17056
    int bid = blockIdx.x;
    int tid = threadIdx.x;
    int tx = tid & 31, ty = tid >> 5;
    if (bid < MS_NB) {
        int bx = bid % MS_BX;
        int t  = bid / MS_BX;
        int by = t % MS_BY;
        int b  = t / MS_BY;
        mscn_body<unsigned char>(y, nrm, H1, W1, bx * 32, by * 32, b, tx, ty, tid,
                                 *reinterpret_cast<MscnS*>(smem));
    } else {
        int rid = bid - MS_NB;
        int jx = rid % RS_BX;
        int t  = rid / RS_BX;
        int iy = t % RS_BY;
        int b  = t / RS_BY;
        resize_body(y, half, jx * 32, iy * 32, b, tid,
                    *reinterpret_cast<ResizeS*>(smem));
    }
}

// ---------------- FEATS phase A body: per-slice partial stats.
// NT threads; rows*TPR threads work (256 for scale-1 32-row slices, 192 for scale-2).
template <int COLS, int TPR, int NT>
__device__ __forceinline__ void fpart_body(const float* __restrict__ p, int W,
                                           int row0, int BSfull, int tid,
                                           float* __restrict__ outp) {
    constexpr int SPAN = 12, CW = 4, NCH = 3;
    constexpr int NW = NT / 64;
    __shared__ float wls[NW][25];
    if (tid < NT) {
        int lane = tid & 63, wv = tid >> 6;
        int li = tid / TPR;
        int c0 = (tid % TPR) * SPAN;
        int gi = row0 + li;
        int gim = (gi == 0) ? BSfull - 1 : gi - 1;
        const float* rowcp = p + (size_t)gi * W;
        const float* rowmp = p + (size_t)gim * W;

        float c2 = rowcp[c0 == 0 ? COLS - 1 : c0 - 1];
        float m2 = rowmp[c0 == 0 ? COLS - 1 : c0 - 1];
        float mrightE = rowmp[c0 + SPAN == COLS ? 0 : c0 + SPAN];

        float sn[5] = {0, 0, 0, 0, 0}, s2[5] = {0, 0, 0, 0, 0}, sa[5] = {0, 0, 0, 0, 0};
        int cneg[5] = {0, 0, 0, 0, 0}, cnz[5] = {0, 0, 0, 0, 0};

        auto PROC = [&](float v0, float cl, float up, float ul, float ur) {
            float v[5] = {v0, v0 * cl, v0 * up, v0 * ul, v0 * ur};
            #pragma unroll
            for (int s = 0; s < 5; s++) {
                float vv = v[s];
                float t = fminf(vv, 0.0f);
                sn[s] += t * t;
                s2[s] += vv * vv;
                sa[s] += fabsf(vv);
                cneg[s] += (int)__popcll(__ballot(vv < 0.0f));
                cnz[s]  += (int)__popcll(__ballot(vv != 0.0f));
            }
        };

        float c1 = 0.0f, m1 = 0.0f;
        #pragma unroll
        for (int j = 0; j < NCH; j++) {
            float cc[CW], mm[CW];
            {
                float4 v = *(const float4*)(rowcp + c0 + j * CW);
                cc[0] = v.x; cc[1] = v.y; cc[2] = v.z; cc[3] = v.w;
            }
            #pragma unroll
            for (int k = 0; k < CW; k++) mm[k] = __shfl_up(cc[k], TPR, 64);
            if (lane < TPR) {
                float4 v = *(const float4*)(rowmp + c0 + j * CW);
                mm[0] = v.x; mm[1] = v.y; mm[2] = v.z; mm[3] = v.w;
            }
            #pragma unroll
            for (int k = 0; k < CW; k++) {
                if (j == 0 && k == 0) { c1 = cc[0]; m1 = mm[0]; }
                else {
                    PROC(c1, c2, m1, m2, mm[k]);
                    c2 = c1; m2 = m1; c1 = cc[k]; m1 = mm[k];
                }
            }
        }
        PROC(c1, c2, m1, m2, mrightE);

        #pragma unroll
        for (int s = 0; s < 5; s++) {
            float vals[3] = {sn[s], s2[s], sa[s]};
            const int rows3[3] = {0, 1, 4};
            #pragma unroll
            for (int m = 0; m < 3; m++) {
                float v = vals[m];
                #pragma unroll
                for (int off = 32; off > 0; off >>= 1) v += __shfl_down(v, off, 64);
                if (lane == 0) wls[wv][s * 5 + rows3[m]] = v;
            }
            if (lane == 0) {
                wls[wv][s * 5 + 2] = (float)cneg[s];
                wls[wv][s * 5 + 3] = (float)cnz[s];
            }
        }
    }
    __syncthreads();
    if (tid < 25) {
        float s = 0.0f;
        #pragma unroll
        for (int w = 0; w < NW; w++) s += wls[w][tid];
        outp[tid] = s;
    }
}

// finalize: ss[25] -> 18 features
__device__ __forceinline__ void finalize_feats(int tid, int BS, const float* ss,
                                               float* srn, float* sls, float* srs,
                                               const float* __restrict__ rgam,
                                               const float* __restrict__ ratio_t,
                                               const float* __restrict__ meanfac_t,
                                               float* __restrict__ fp) {
    if (tid < 5) {
        int s = tid;
        float SN  = ss[s * 5 + 0];
        float S2  = ss[s * 5 + 1];
        float CN  = ss[s * 5 + 2];
        float CNZ = ss[s * 5 + 3];
        float SA  = ss[s * 5 + 4];
        float SP = S2 - SN;
        float CP = CNZ - CN;
        float ls = sqrtf(SN / CN);
        float rs = sqrtf(SP / CP);
        float gh = ls / rs;
        float Nn = (float)(BS * BS);
        float am = SA / Nn;
        float rhat = (am * am) / (S2 / Nn);
        float g2 = gh * gh;
        float rn = rhat * (g2 * gh + 1.0f) * (gh + 1.0f) / ((g2 + 1.0f) * (g2 + 1.0f));
        srn[s] = rn; sls[s] = ls; srs[s] = rs;
    }
    __syncthreads();
    if (tid < 64) {
        int lane = tid;
        for (int s = 0; s < 5; s++) {
            float rn = srn[s];
            int lo = -1, hi = NGAM;
            while (hi - lo > 1) {
                int n = hi - lo - 1;
                int stride = n / 65 + 1;
                int pi = lo + (lane + 1) * stride;
                bool valid = pi < hi;
                float v = valid ? rgam[pi] : 0.0f;
                unsigned long long blw = __ballot(valid && (v < rn));
                int k = __popcll(blw);
                int oldlo = lo;
                lo = oldlo + k * stride;
                int cand = oldlo + (k + 1) * stride;
                if (cand < hi) hi = cand;
            }
            int lb = hi;
            int ix;
            if (lb <= 0) ix = 0;
            else if (lb >= NGAM) ix = NGAM - 1;
            else {
                float dl = rgam[lb - 1] - rn, dr = rgam[lb] - rn;
                ix = (dl * dl <= dr * dr) ? lb - 1 : lb;
            }
            if (lane == 0) {
                float a = (float)ix * 0.001f + 0.2f;
                float ratio = ratio_t[ix];
                float bl = sls[s] * ratio;
                float br = srs[s] * ratio;
                if (s == 0) {
                    fp[0] = a; fp[1] = 0.5f * (bl + br);
                } else {
                    float mn = (br - bl) * meanfac_t[ix];
                    int base = 2 + (s - 1) * 4;
                    fp[base] = a; fp[base + 1] = mn; fp[base + 2] = bl; fp[base + 3] = br;
                }
            }
        }
    }
}

// ---------------- merged: fpart scale-1 (2640 blocks, 32-row slices, all 256 threads
// active) + mscn2 (2040 blocks)
__global__ __launch_bounds__(256) void k_mscn2_fpart1(const float* __restrict__ nrm,
                                                      const float* __restrict__ half,
                                                      float* __restrict__ nrm2,
                                                      float* __restrict__ part) {
    __shared__ __align__(16) char smem[sizeof(MscnS)];
    int bid = blockIdx.x, tid = threadIdx.x;
    if (bid < NPART1) {
        int g = bid / NSL1, sl = bid % NSL1;
        int b = g / NBLK, r = g % NBLK;
        const float* p = nrm + (size_t)b * H1 * W1 + (size_t)(r / NBW * 96) * W1
                       + (size_t)(r % NBW) * 96;
        fpart_body<96, 8, 256>(p, W1, sl * 32, 96, tid, part + (size_t)bid * 25);
    } else {
        int rid = bid - NPART1;
        int jx = rid % RS_BX;
        int t  = rid / RS_BX;
        int iy = t % RS_BY;
        int b  = t / RS_BY;
        mscn_body<float>(half, nrm2, H2, W2, jx * 32, iy * 32, b,
                         tid & 31, tid >> 5, tid, *reinterpret_cast<MscnS*>(smem));
    }
}

// ---------------- merged: fpart scale-2 with INTRA-BLOCK finalize (880) + ffinal scale-1 (880)
__global__ __launch_bounds__(192) void k_fpart2_ffinal1(const float* __restrict__ nrm2,
                                                        const float* __restrict__ part,
                                                        const float* __restrict__ rgam,
                                                        const float* __restrict__ ratio_t,
                                                        const float* __restrict__ meanfac_t,
                                                        float* __restrict__ feats) {
    __shared__ float ss[25];
    __shared__ float srn[5], sls[5], srs[5];
    int bid = blockIdx.x, tid = threadIdx.x;
    if (bid < NB * NBLK) {
        int g = bid;
        int b = g / NBLK, r = g % NBLK;
        const float* p = nrm2 + (size_t)b * H2 * W2 + (size_t)(r / NBW * 48) * W2
                       + (size_t)(r % NBW) * 48;
        fpart_body<48, 4, 192>(p, W2, 0, 48, tid, ss);
        __syncthreads();
        finalize_feats(tid, 48, ss, srn, sls, srs, rgam, ratio_t, meanfac_t,
                       feats + (size_t)g * NF + 18);
    } else {
        int g = bid - NB * NBLK;
        if (tid < 25) {
            float s = 0.0f;
            #pragma unroll
            for (int sl = 0; sl < NSL1; sl++)
                s += part[(size_t)(g * NSL1 + sl) * 25 + tid];
            ss[tid] = s;
        }
        __syncthreads();
        finalize_feats(tid, 96, ss, srn, sls, srs, rgam, ratio_t, meanfac_t,
                       feats + (size_t)g * NF + 0);
    }
}

// ---------------- per-batch stats: cov via transposed dist + 3x3 register tiles,
// then no-pivot Gauss-Jordan (M is SPD), f32 throughout.
__global__ __launch_bounds__(256) void k_stats(const float* __restrict__ feats,
                                               const float* __restrict__ mu_pris,
                                               const float* __restrict__ cov_pris,
                                               float* __restrict__ out) {
    __shared__ float dist[NBLK * NF];
    __shared__ __align__(16) float distT[NF][228];
    __shared__ float mu[NF];
    __shared__ float M[NF][NF + 1];
    __shared__ float facs[NF];
    __shared__ float dd[NF];

    int b = blockIdx.x, tid = threadIdx.x;
    for (int t = tid; t < NBLK * NF; t += 256) dist[t] = feats[(size_t)b * NBLK * NF + t];
    __syncthreads();
    if (tid < NF) {
        float s = 0.0f;
        for (int n = 0; n < NBLK; n++) s += dist[n * NF + tid];
        mu[tid] = s / (float)NBLK;
    }
    __syncthreads();
    for (int t = tid; t < NF * NBLK; t += 256) {
        int f = t / NBLK, n = t % NBLK;
        distT[f][n] = dist[n * NF + f] - mu[f];
    }
    __syncthreads();

    if (tid < 144) {
        int f0 = (tid / 12) * 3, g0 = (tid % 12) * 3;
        float acc[3][3] = {{0,0,0},{0,0,0},{0,0,0}};
        for (int n = 0; n < NBLK; n += 4) {
            float4 A[3], B[3];
            #pragma unroll
            for (int i = 0; i < 3; i++) A[i] = *(const float4*)&distT[f0 + i][n];
            #pragma unroll
            for (int j = 0; j < 3; j++) B[j] = *(const float4*)&distT[g0 + j][n];
            #pragma unroll
            for (int i = 0; i < 3; i++)
                #pragma unroll
                for (int j = 0; j < 3; j++)
                    acc[i][j] += A[i].x * B[j].x + A[i].y * B[j].y
                               + A[i].z * B[j].z + A[i].w * B[j].w;
        }
        const float* cp = cov_pris + (size_t)b * NF * NF;
        #pragma unroll
        for (int i = 0; i < 3; i++)
            #pragma unroll
            for (int j = 0; j < 3; j++) {
                int f = f0 + i, gg = g0 + j;
                M[f][gg] = (cp[f * NF + gg] + acc[i][j] / (float)(NBLK - 1)) * 0.5f;
            }
    }
    if (tid < NF) {
        float d = mu_pris[b * NF + tid] - mu[tid];
        dd[tid] = d;
        M[tid][NF] = d;
    }
    __syncthreads();

    for (int k = 0; k < NF; k++) {
        if (tid < NF && tid != k) facs[tid] = M[tid][k] / M[k][k];
        __syncthreads();
        for (int t = tid; t < NF * (NF + 1); t += 256) {
            int i = t / (NF + 1), j = t % (NF + 1);
            if (i != k && j > k) M[i][j] -= facs[i] * M[k][j];
        }
        __syncthreads();
    }

    if (tid < 64) {
        double c = (tid < NF) ? (double)dd[tid] * ((double)M[tid][NF] / (double)M[tid][tid]) : 0.0;
        #pragma unroll
        for (int off = 32; off > 0; off >>= 1) c += __shfl_down(c, off, 64);
        if (tid == 0) out[b] = (float)sqrt(c);
    }
}

extern "C" void kernel_launch(void* const* d_in, const int* in_sizes, int n_in,
                              void* d_out, int out_size, void* d_ws, size_t ws_size,
                              hipStream_t stream) {
    const float* x        = (const float*)d_in[0];
    const float* mu_pris  = (const float*)d_in[1];
    const float* cov_pris = (const float*)d_in[2];
    float* out = (float*)d_out;
    float* ws  = (float*)d_ws;

    unsigned char* y8 = (unsigned char*)ws;               // NB*H1*W1 bytes
    float* nrm   = ws + (size_t)NB * H1 * W1 / 4;         // 8,110,080 floats
    float* half  = nrm + (size_t)NB * H1 * W1;            // 2,027,520
    float* nrm2  = half + (size_t)NB * H2 * W2;           // 2,027,520
    float* rgam  = nrm2 + (size_t)NB * H2 * W2;           // 9801
    float* ratio = rgam + NGAM;                           // 9801
    float* mfac  = ratio + NGAM;                          // 9801
    float* feats = mfac + NGAM;                           // NB*220*36 = 31,680
    float* part  = feats + (size_t)NB * NBLK * NF;        // 2640*25 = 66,000

    const int NGB8 = NB * H1 * (W1 / 8);
    k_gray_rgam<<<(NGB8 + NGAM + 255) / 256, 256, 0, stream>>>(
        (const float4*)x, (uint2*)y8, rgam, ratio, mfac);

    k_ms_rs<<<MS_NB + RS_NB, 256, 0, stream>>>(y8, nrm, half);

    k_mscn2_fpart1<<<NPART1 + RS_NB, 256, 0, stream>>>(nrm, half, nrm2, part);

    k_fpart2_ffinal1<<<2 * NB * NBLK, 192, 0, stream>>>(nrm2, part, rgam, ratio, mfac, feats);

    k_stats<<<NB, 256, 0, stream>>>(feats, mu_pris, cov_pris, out);
}

// Round 19
// 154.430 us; speedup vs baseline: 2.1774x; 1.0081x over previous
//
#include <hip/hip_runtime.h>
#include <hip/hip_fp16.h>
#include <math.h>

#define NB   4
#define H1   1056
#define W1   1920
#define H2   528
#define W2   960
#define NBLK 220    // 11*20 blocks per image, both scales
#define NBW  20
#define NF   36
#define NGAM 9801
#define NSL1 3      // row-slices per 96-block (32 rows each -> 256 threads exactly)
#define NPART1 (NB * NBLK * NSL1)               // 2640 scale-1 slice partials

#define MS_BX (W1 / 32)            // 60
#define MS_BY (H1 / 32)            // 33
#define MS_NB (MS_BX * MS_BY * NB) // 7920
#define RS_BX (W2 / 32)            // 30
#define RS_BY ((H2 + 31) / 32)     // 17
#define RS_NB (RS_BX * RS_BY * NB) // 2040

__device__ __forceinline__ int reflect_idx(int i, int n) {
    if (i < 0) return -i - 1;
    if (i >= n) return 2 * n - i - 1;
    return i;
}

__device__ __forceinline__ float ldf(const unsigned char* p) { return (float)*p; }
__device__ __forceinline__ float ldf(const __half* p)        { return __half2float(*p); }
__device__ __forceinline__ float ldf(const float* p)         { return *p; }

// ---------------- gray (8 px/thread, uchar8 output) + R_GAM tables in one launch.
// y values are rintf() results in [0,255] -> uchar roundtrip is bitwise exact.
__global__ void k_gray_rgam(const float4* __restrict__ x, uint2* __restrict__ y8,
                            float* __restrict__ rg, float* __restrict__ rt,
                            float* __restrict__ mf) {
    const int W8 = W1 / 8;                 // 240
    const int W4 = W1 / 4;                 // 480
    const int gtotal = NB * H1 * W8;
    int idx = blockIdx.x * 256 + threadIdx.x;
    if (idx < gtotal) {
        int w8 = idx % W8;
        int t  = idx / W8;
        int h  = t % H1;
        int b  = t / H1;
        size_t base = ((size_t)(b * 3) * 1080 + h) * W4 + w8 * 2;
        float4 r0 = x[base],                     r1 = x[base + 1];
        float4 g0 = x[base + (size_t)1080 * W4], g1 = x[base + (size_t)1080 * W4 + 1];
        float4 b0 = x[base + 2 * (size_t)1080 * W4], b1 = x[base + 2 * (size_t)1080 * W4 + 1];
        unsigned int v0, v1;
        {
            unsigned int a = (unsigned int)rintf((0.299f * r0.x + 0.587f * g0.x + 0.114f * b0.x) * 255.0f);
            unsigned int b_ = (unsigned int)rintf((0.299f * r0.y + 0.587f * g0.y + 0.114f * b0.y) * 255.0f);
            unsigned int c = (unsigned int)rintf((0.299f * r0.z + 0.587f * g0.z + 0.114f * b0.z) * 255.0f);
            unsigned int d = (unsigned int)rintf((0.299f * r0.w + 0.587f * g0.w + 0.114f * b0.w) * 255.0f);
            v0 = a | (b_ << 8) | (c << 16) | (d << 24);
        }
        {
            unsigned int a = (unsigned int)rintf((0.299f * r1.x + 0.587f * g1.x + 0.114f * b1.x) * 255.0f);
            unsigned int b_ = (unsigned int)rintf((0.299f * r1.y + 0.587f * g1.y + 0.114f * b1.y) * 255.0f);
            unsigned int c = (unsigned int)rintf((0.299f * r1.z + 0.587f * g1.z + 0.114f * b1.z) * 255.0f);
            unsigned int d = (unsigned int)rintf((0.299f * r1.w + 0.587f * g1.w + 0.114f * b1.w) * 255.0f);
            v1 = a | (b_ << 8) | (c << 16) | (d << 24);
        }
        y8[idx] = make_uint2(v0, v1);
    } else {
        int i = idx - gtotal;
        if (i < NGAM) {
            float g = (float)i * 0.001f + 0.2f;
            float l1 = lgammaf(1.0f / g);
            float l2 = lgammaf(2.0f / g);
            float l3 = lgammaf(3.0f / g);
            rg[i] = expf(2.0f * l2 - l1 - l3);
            rt[i] = expf(0.5f * (l1 - l3));
            mf[i] = expf(l2 - l1);
        }
    }
}

// ---------------- MSCN body (register-blocked separable 7-tap), templated source type,
// fp16 output (storage only; all arithmetic f32).
struct MscnS {
    float tile[38][40];
    float h1s[38][36];
    float h2s[38][36];
    float gw1[8];
};
struct ResizeS {
    float yt[70][72];
    float vv[32][72];
};

template <typename TIN>
__device__ __forceinline__ void mscn_body(const TIN* __restrict__ src,
                                          __half* __restrict__ out, int H, int W,
                                          int ox0, int oy0, int b,
                                          int tx, int ty, int tid, MscnS& S) {
    if (tid < 7) {
        double s = 7.0 / 6.0;
        double sum = 0.0;
        #pragma unroll
        for (int k = 0; k < 7; k++) sum += exp(-(double)((k - 3) * (k - 3)) / (2.0 * s * s));
        double e = exp(-(double)((tid - 3) * (tid - 3)) / (2.0 * s * s));
        S.gw1[tid] = (float)(e / sum);
    }

    const TIN* p = src + (size_t)b * H * W;
    for (int t = tid; t < 38 * 38; t += 256) {
        int r = t / 38, c = t % 38;
        int gr = oy0 - 3 + r; gr = gr < 0 ? 0 : (gr >= H ? H - 1 : gr);
        int gc = ox0 - 3 + c; gc = gc < 0 ? 0 : (gc >= W ? W - 1 : gc);
        S.tile[r][c] = ldf(&p[(size_t)gr * W + gc]);
    }
    __syncthreads();

    for (int t = tid; t < 38 * 8; t += 256) {
        int r = t / 8, c0 = (t % 8) * 4;
        float4 f0 = *(const float4*)&S.tile[r][c0];
        float4 f1 = *(const float4*)&S.tile[r][c0 + 4];
        float2 f2 = *(const float2*)&S.tile[r][c0 + 8];
        float v[10] = {f0.x, f0.y, f0.z, f0.w, f1.x, f1.y, f1.z, f1.w, f2.x, f2.y};
        float s1[4] = {0, 0, 0, 0}, s2[4] = {0, 0, 0, 0};
        #pragma unroll
        for (int k = 0; k < 7; k++) {
            float w = S.gw1[k];
            #pragma unroll
            for (int s = 0; s < 4; s++) {
                float vv = v[s + k];
                s1[s] += w * vv;
                s2[s] += w * vv * vv;
            }
        }
        *(float4*)&S.h1s[r][c0] = make_float4(s1[0], s1[1], s1[2], s1[3]);
        *(float4*)&S.h2s[r][c0] = make_float4(s2[0], s2[1], s2[2], s2[3]);
    }
    __syncthreads();

    int ly0 = ty * 4;
    float a1[10], a2[10];
    #pragma unroll
    for (int k = 0; k < 10; k++) { a1[k] = S.h1s[ly0 + k][tx]; a2[k] = S.h2s[ly0 + k][tx]; }
    __half* q = out + (size_t)b * H * W;
    #pragma unroll
    for (int s = 0; s < 4; s++) {
        int oy = oy0 + ly0 + s, ox = ox0 + tx;
        if (oy < H) {
            float m1 = 0.0f, m2 = 0.0f;
            #pragma unroll
            for (int k = 0; k < 7; k++) {
                float w = S.gw1[k];
                m1 += w * a1[s + k];
                m2 += w * a2[s + k];
            }
            float sig = sqrtf(fabsf(m2 - m1 * m1));
            q[(size_t)oy * W + ox] = __float2half((S.tile[ly0 + s + 3][tx + 3] - m1) / (sig + 1.0f));
        }
    }
}

__device__ const float RW8[8] = {-0.01171875f, -0.03515625f, 0.11328125f, 0.43359375f,
                                  0.43359375f,  0.11328125f, -0.03515625f, -0.01171875f};

__device__ __forceinline__ void resize_body(const unsigned char* __restrict__ y,
                                            __half* __restrict__ half,
                                            int j0, int i0, int b, int tid, ResizeS& S) {
    const unsigned char* py = y + (size_t)b * H1 * W1;
    int rbase = 2 * i0 - 3, cbase = 2 * j0 - 3;

    for (int t = tid; t < 70 * 70; t += 256) {
        int r = t / 70, c = t % 70;
        int gr = reflect_idx(rbase + r, H1);
        int gc = reflect_idx(cbase + c, W1);
        S.yt[r][c] = (float)py[(size_t)gr * W1 + gc] / 255.0f;
    }
    __syncthreads();

    for (int t = tid; t < 32 * 70; t += 256) {
        int i = t / 70, c = t % 70;
        float acc = 0.0f;
        #pragma unroll
        for (int p = 0; p < 8; p++) acc += RW8[p] * S.yt[2 * i + p][c];
        S.vv[i][c] = acc;
    }
    __syncthreads();

    __half* ph = half + (size_t)b * H2 * W2;
    for (int t = tid; t < 1024; t += 256) {
        int i = t >> 5, j = t & 31;
        int oy = i0 + i, ox = j0 + j;
        if (oy < H2 && ox < W2) {
            float acc = 0.0f;
            #pragma unroll
            for (int p = 0; p < 8; p++) acc += RW8[p] * S.vv[i][2 * j + p];
            ph[(size_t)oy * W2 + ox] = __float2half(acc * 255.0f);
        }
    }
}

// merged mscn1 + resize (both consume uchar y, independent of each other)
__global__ __launch_bounds__(256) void k_ms_rs(const unsigned char* __restrict__ y,
                                               __half* __restrict__ nrm,
                                               __half* __restrict__ half) {
    __shared__ __align__(16) char smem[sizeof(ResizeS)];   // 29376 > 17056
    int bid = blockIdx.x;
    int tid = threadIdx.x;
    int tx = tid & 31, ty = tid >> 5;
    if (bid < MS_NB) {
        int bx = bid % MS_BX;
        int t  = bid / MS_BX;
        int by = t % MS_BY;
        int b  = t / MS_BY;
        mscn_body<unsigned char>(y, nrm, H1, W1, bx * 32, by * 32, b, tx, ty, tid,
                                 *reinterpret_cast<MscnS*>(smem));
    } else {
        int rid = bid - MS_NB;
        int jx = rid % RS_BX;
        int t  = rid / RS_BX;
        int iy = t % RS_BY;
        int b  = t / RS_BY;
        resize_body(y, half, jx * 32, iy * 32, b, tid,
                    *reinterpret_cast<ResizeS*>(smem));
    }
}

// ---------------- FEATS phase A body: per-slice partial stats over fp16 norm
// (converted to f32 on load; all accumulation f32 — identical expressions).
template <int COLS, int TPR, int NT>
__device__ __forceinline__ void fpart_body(const __half* __restrict__ p, int W,
                                           int row0, int BSfull, int tid,
                                           float* __restrict__ outp) {
    constexpr int SPAN = 12, CW = 4, NCH = 3;
    constexpr int NW = NT / 64;
    __shared__ float wls[NW][25];
    if (tid < NT) {
        int lane = tid & 63, wv = tid >> 6;
        int li = tid / TPR;
        int c0 = (tid % TPR) * SPAN;
        int gi = row0 + li;
        int gim = (gi == 0) ? BSfull - 1 : gi - 1;
        const __half* rowcp = p + (size_t)gi * W;
        const __half* rowmp = p + (size_t)gim * W;

        float c2 = __half2float(rowcp[c0 == 0 ? COLS - 1 : c0 - 1]);
        float m2 = __half2float(rowmp[c0 == 0 ? COLS - 1 : c0 - 1]);
        float mrightE = __half2float(rowmp[c0 + SPAN == COLS ? 0 : c0 + SPAN]);

        float sn[5] = {0, 0, 0, 0, 0}, s2[5] = {0, 0, 0, 0, 0}, sa[5] = {0, 0, 0, 0, 0};
        int cneg[5] = {0, 0, 0, 0, 0}, cnz[5] = {0, 0, 0, 0, 0};

        auto PROC = [&](float v0, float cl, float up, float ul, float ur) {
            float v[5] = {v0, v0 * cl, v0 * up, v0 * ul, v0 * ur};
            #pragma unroll
            for (int s = 0; s < 5; s++) {
                float vv = v[s];
                float t = fminf(vv, 0.0f);
                sn[s] += t * t;
                s2[s] += vv * vv;
                sa[s] += fabsf(vv);
                cneg[s] += (int)__popcll(__ballot(vv < 0.0f));
                cnz[s]  += (int)__popcll(__ballot(vv != 0.0f));
            }
        };

        float c1 = 0.0f, m1 = 0.0f;
        #pragma unroll
        for (int j = 0; j < NCH; j++) {
            float cc[CW], mm[CW];
            {
                __half2 u0 = *(const __half2*)(rowcp + c0 + j * CW);
                __half2 u1 = *(const __half2*)(rowcp + c0 + j * CW + 2);
                float2 f0 = __half22float2(u0), f1 = __half22float2(u1);
                cc[0] = f0.x; cc[1] = f0.y; cc[2] = f1.x; cc[3] = f1.y;
            }
            #pragma unroll
            for (int k = 0; k < CW; k++) mm[k] = __shfl_up(cc[k], TPR, 64);
            if (lane < TPR) {
                __half2 u0 = *(const __half2*)(rowmp + c0 + j * CW);
                __half2 u1 = *(const __half2*)(rowmp + c0 + j * CW + 2);
                float2 f0 = __half22float2(u0), f1 = __half22float2(u1);
                mm[0] = f0.x; mm[1] = f0.y; mm[2] = f1.x; mm[3] = f1.y;
            }
            #pragma unroll
            for (int k = 0; k < CW; k++) {
                if (j == 0 && k == 0) { c1 = cc[0]; m1 = mm[0]; }
                else {
                    PROC(c1, c2, m1, m2, mm[k]);
                    c2 = c1; m2 = m1; c1 = cc[k]; m1 = mm[k];
                }
            }
        }
        PROC(c1, c2, m1, m2, mrightE);

        #pragma unroll
        for (int s = 0; s < 5; s++) {
            float vals[3] = {sn[s], s2[s], sa[s]};
            const int rows3[3] = {0, 1, 4};
            #pragma unroll
            for (int m = 0; m < 3; m++) {
                float v = vals[m];
                #pragma unroll
                for (int off = 32; off > 0; off >>= 1) v += __shfl_down(v, off, 64);
                if (lane == 0) wls[wv][s * 5 + rows3[m]] = v;
            }
            if (lane == 0) {
                wls[wv][s * 5 + 2] = (float)cneg[s];
                wls[wv][s * 5 + 3] = (float)cnz[s];
            }
        }
    }
    __syncthreads();
    if (tid < 25) {
        float s = 0.0f;
        #pragma unroll
        for (int w = 0; w < NW; w++) s += wls[w][tid];
        outp[tid] = s;
    }
}

// finalize: ss[25] -> 18 features
__device__ __forceinline__ void finalize_feats(int tid, int BS, const float* ss,
                                               float* srn, float* sls, float* srs,
                                               const float* __restrict__ rgam,
                                               const float* __restrict__ ratio_t,
                                               const float* __restrict__ meanfac_t,
                                               float* __restrict__ fp) {
    if (tid < 5) {
        int s = tid;
        float SN  = ss[s * 5 + 0];
        float S2  = ss[s * 5 + 1];
        float CN  = ss[s * 5 + 2];
        float CNZ = ss[s * 5 + 3];
        float SA  = ss[s * 5 + 4];
        float SP = S2 - SN;
        float CP = CNZ - CN;
        float ls = sqrtf(SN / CN);
        float rs = sqrtf(SP / CP);
        float gh = ls / rs;
        float Nn = (float)(BS * BS);
        float am = SA / Nn;
        float rhat = (am * am) / (S2 / Nn);
        float g2 = gh * gh;
        float rn = rhat * (g2 * gh + 1.0f) * (gh + 1.0f) / ((g2 + 1.0f) * (g2 + 1.0f));
        srn[s] = rn; sls[s] = ls; srs[s] = rs;
    }
    __syncthreads();
    if (tid < 64) {
        int lane = tid;
        for (int s = 0; s < 5; s++) {
            float rn = srn[s];
            int lo = -1, hi = NGAM;
            while (hi - lo > 1) {
                int n = hi - lo - 1;
                int stride = n / 65 + 1;
                int pi = lo + (lane + 1) * stride;
                bool valid = pi < hi;
                float v = valid ? rgam[pi] : 0.0f;
                unsigned long long blw = __ballot(valid && (v < rn));
                int k = __popcll(blw);
                int oldlo = lo;
                lo = oldlo + k * stride;
                int cand = oldlo + (k + 1) * stride;
                if (cand < hi) hi = cand;
            }
            int lb = hi;
            int ix;
            if (lb <= 0) ix = 0;
            else if (lb >= NGAM) ix = NGAM - 1;
            else {
                float dl = rgam[lb - 1] - rn, dr = rgam[lb] - rn;
                ix = (dl * dl <= dr * dr) ? lb - 1 : lb;
            }
            if (lane == 0) {
                float a = (float)ix * 0.001f + 0.2f;
                float ratio = ratio_t[ix];
                float bl = sls[s] * ratio;
                float br = srs[s] * ratio;
                if (s == 0) {
                    fp[0] = a; fp[1] = 0.5f * (bl + br);
                } else {
                    float mn = (br - bl) * meanfac_t[ix];
                    int base = 2 + (s - 1) * 4;
                    fp[base] = a; fp[base + 1] = mn; fp[base + 2] = bl; fp[base + 3] = br;
                }
            }
        }
    }
}

// ---------------- merged: fpart scale-1 (2640 blocks, 32-row slices, all 256 threads
// active) + mscn2 (2040 blocks)
__global__ __launch_bounds__(256) void k_mscn2_fpart1(const __half* __restrict__ nrm,
                                                      const __half* __restrict__ half,
                                                      __half* __restrict__ nrm2,
                                                      float* __restrict__ part) {
    __shared__ __align__(16) char smem[sizeof(MscnS)];
    int bid = blockIdx.x, tid = threadIdx.x;
    if (bid < NPART1) {
        int g = bid / NSL1, sl = bid % NSL1;
        int b = g / NBLK, r = g % NBLK;
        const __half* p = nrm + (size_t)b * H1 * W1 + (size_t)(r / NBW * 96) * W1
                        + (size_t)(r % NBW) * 96;
        fpart_body<96, 8, 256>(p, W1, sl * 32, 96, tid, part + (size_t)bid * 25);
    } else {
        int rid = bid - NPART1;
        int jx = rid % RS_BX;
        int t  = rid / RS_BX;
        int iy = t % RS_BY;
        int b  = t / RS_BY;
        mscn_body<__half>(half, nrm2, H2, W2, jx * 32, iy * 32, b,
                          tid & 31, tid >> 5, tid, *reinterpret_cast<MscnS*>(smem));
    }
}

// ---------------- merged: fpart scale-2 with INTRA-BLOCK finalize (880) + ffinal scale-1 (880)
__global__ __launch_bounds__(192) void k_fpart2_ffinal1(const __half* __restrict__ nrm2,
                                                        const float* __restrict__ part,
                                                        const float* __restrict__ rgam,
                                                        const float* __restrict__ ratio_t,
                                                        const float* __restrict__ meanfac_t,
                                                        float* __restrict__ feats) {
    __shared__ float ss[25];
    __shared__ float srn[5], sls[5], srs[5];
    int bid = blockIdx.x, tid = threadIdx.x;
    if (bid < NB * NBLK) {
        int g = bid;
        int b = g / NBLK, r = g % NBLK;
        const __half* p = nrm2 + (size_t)b * H2 * W2 + (size_t)(r / NBW * 48) * W2
                        + (size_t)(r % NBW) * 48;
        fpart_body<48, 4, 192>(p, W2, 0, 48, tid, ss);
        __syncthreads();
        finalize_feats(tid, 48, ss, srn, sls, srs, rgam, ratio_t, meanfac_t,
                       feats + (size_t)g * NF + 18);
    } else {
        int g = bid - NB * NBLK;
        if (tid < 25) {
            float s = 0.0f;
            #pragma unroll
            for (int sl = 0; sl < NSL1; sl++)
                s += part[(size_t)(g * NSL1 + sl) * 25 + tid];
            ss[tid] = s;
        }
        __syncthreads();
        finalize_feats(tid, 96, ss, srn, sls, srs, rgam, ratio_t, meanfac_t,
                       feats + (size_t)g * NF + 0);
    }
}

// ---------------- per-batch stats: cov via transposed dist + 3x3 register tiles,
// then no-pivot Gauss-Jordan (M is SPD), f32 throughout.
__global__ __launch_bounds__(256) void k_stats(const float* __restrict__ feats,
                                               const float* __restrict__ mu_pris,
                                               const float* __restrict__ cov_pris,
                                               float* __restrict__ out) {
    __shared__ float dist[NBLK * NF];
    __shared__ __align__(16) float distT[NF][228];
    __shared__ float mu[NF];
    __shared__ float M[NF][NF + 1];
    __shared__ float facs[NF];
    __shared__ float dd[NF];

    int b = blockIdx.x, tid = threadIdx.x;
    for (int t = tid; t < NBLK * NF; t += 256) dist[t] = feats[(size_t)b * NBLK * NF + t];
    __syncthreads();
    if (tid < NF) {
        float s = 0.0f;
        for (int n = 0; n < NBLK; n++) s += dist[n * NF + tid];
        mu[tid] = s / (float)NBLK;
    }
    __syncthreads();
    for (int t = tid; t < NF * NBLK; t += 256) {
        int f = t / NBLK, n = t % NBLK;
        distT[f][n] = dist[n * NF + f] - mu[f];
    }
    __syncthreads();

    if (tid < 144) {
        int f0 = (tid / 12) * 3, g0 = (tid % 12) * 3;
        float acc[3][3] = {{0,0,0},{0,0,0},{0,0,0}};
        for (int n = 0; n < NBLK; n += 4) {
            float4 A[3], B[3];
            #pragma unroll
            for (int i = 0; i < 3; i++) A[i] = *(const float4*)&distT[f0 + i][n];
            #pragma unroll
            for (int j = 0; j < 3; j++) B[j] = *(const float4*)&distT[g0 + j][n];
            #pragma unroll
            for (int i = 0; i < 3; i++)
                #pragma unroll
                for (int j = 0; j < 3; j++)
                    acc[i][j] += A[i].x * B[j].x + A[i].y * B[j].y
                               + A[i].z * B[j].z + A[i].w * B[j].w;
        }
        const float* cp = cov_pris + (size_t)b * NF * NF;
        #pragma unroll
        for (int i = 0; i < 3; i++)
            #pragma unroll
            for (int j = 0; j < 3; j++) {
                int f = f0 + i, gg = g0 + j;
                M[f][gg] = (cp[f * NF + gg] + acc[i][j] / (float)(NBLK - 1)) * 0.5f;
            }
    }
    if (tid < NF) {
        float d = mu_pris[b * NF + tid] - mu[tid];
        dd[tid] = d;
        M[tid][NF] = d;
    }
    __syncthreads();

    for (int k = 0; k < NF; k++) {
        if (tid < NF && tid != k) facs[tid] = M[tid][k] / M[k][k];
        __syncthreads();
        for (int t = tid; t < NF * (NF + 1); t += 256) {
            int i = t / (NF + 1), j = t % (NF + 1);
            if (i != k && j > k) M[i][j] -= facs[i] * M[k][j];
        }
        __syncthreads();
    }

    if (tid < 64) {
        double c = (tid < NF) ? (double)dd[tid] * ((double)M[tid][NF] / (double)M[tid][tid]) : 0.0;
        #pragma unroll
        for (int off = 32; off > 0; off >>= 1) c += __shfl_down(c, off, 64);
        if (tid == 0) out[b] = (float)sqrt(c);
    }
}

extern "C" void kernel_launch(void* const* d_in, const int* in_sizes, int n_in,
                              void* d_out, int out_size, void* d_ws, size_t ws_size,
                              hipStream_t stream) {
    const float* x        = (const float*)d_in[0];
    const float* mu_pris  = (const float*)d_in[1];
    const float* cov_pris = (const float*)d_in[2];
    float* out = (float*)d_out;

    char* base = (char*)d_ws;
    unsigned char* y8 = (unsigned char*)base;                       // 8,110,080 B
    __half* nrm  = (__half*)(base + 8110080);                       // 16,220,160 B
    __half* half = (__half*)(base + 8110080 + 16220160);            // 4,055,040 B
    __half* nrm2 = half + (size_t)NB * H2 * W2;                     // 4,055,040 B
    float* rgam  = (float*)((char*)nrm2 + (size_t)NB * H2 * W2 * 2);
    float* ratio = rgam + NGAM;
    float* mfac  = ratio + NGAM;
    float* feats = mfac + NGAM;                                     // NB*220*36
    float* part  = feats + (size_t)NB * NBLK * NF;                  // 2640*25

    const int NGB8 = NB * H1 * (W1 / 8);
    k_gray_rgam<<<(NGB8 + NGAM + 255) / 256, 256, 0, stream>>>(
        (const float4*)x, (uint2*)y8, rgam, ratio, mfac);

    k_ms_rs<<<MS_NB + RS_NB, 256, 0, stream>>>(y8, nrm, half);

    k_mscn2_fpart1<<<NPART1 + RS_NB, 256, 0, stream>>>(nrm, half, nrm2, part);

    k_fpart2_ffinal1<<<2 * NB * NBLK, 192, 0, stream>>>(nrm2, part, rgam, ratio, mfac, feats);

    k_stats<<<NB, 256, 0, stream>>>(feats, mu_pris, cov_pris, out);
}

// Round 20
// 148.706 us; speedup vs baseline: 2.2612x; 1.0385x over previous
//
#include <hip/hip_runtime.h>
#include <hip/hip_fp16.h>
#include <math.h>

#define NB   4
#define H1   1056
#define W1   1920
#define H2   528
#define W2   960
#define NBLK 220    // 11*20 blocks per image, both scales
#define NBW  20
#define NF   36
#define NGAM 9801
#define NSL1 3      // row-slices per 96-block (32 rows each -> 256 threads exactly)
#define NPART1 (NB * NBLK * NSL1)               // 2640 scale-1 slice partials

#define MS_BX (W1 / 32)            // 60
#define MS_BY (H1 / 32)            // 33
#define MS_NB (MS_BX * MS_BY * NB) // 7920
#define RS_BX (W2 / 32)            // 30
#define RS_BY ((H2 + 31) / 32)     // 17
#define RS_NB (RS_BX * RS_BY * NB) // 2040

__device__ __forceinline__ int reflect_idx(int i, int n) {
    if (i < 0) return -i - 1;
    if (i >= n) return 2 * n - i - 1;
    return i;
}

__device__ __forceinline__ float ldf(const unsigned char* p) { return (float)*p; }
__device__ __forceinline__ float ldf(const __half* p)        { return __half2float(*p); }
__device__ __forceinline__ float ldf(const float* p)         { return *p; }

// ---------------- gray (8 px/thread, uchar8 output) + R_GAM tables in one launch.
// y values are rintf() results in [0,255] -> uchar roundtrip is bitwise exact.
__global__ void k_gray_rgam(const float4* __restrict__ x, uint2* __restrict__ y8,
                            float* __restrict__ rg, float* __restrict__ rt,
                            float* __restrict__ mf) {
    const int W8 = W1 / 8;                 // 240
    const int W4 = W1 / 4;                 // 480
    const int gtotal = NB * H1 * W8;
    int idx = blockIdx.x * 256 + threadIdx.x;
    if (idx < gtotal) {
        int w8 = idx % W8;
        int t  = idx / W8;
        int h  = t % H1;
        int b  = t / H1;
        size_t base = ((size_t)(b * 3) * 1080 + h) * W4 + w8 * 2;
        float4 r0 = x[base],                     r1 = x[base + 1];
        float4 g0 = x[base + (size_t)1080 * W4], g1 = x[base + (size_t)1080 * W4 + 1];
        float4 b0 = x[base + 2 * (size_t)1080 * W4], b1 = x[base + 2 * (size_t)1080 * W4 + 1];
        unsigned int v0, v1;
        {
            unsigned int a = (unsigned int)rintf((0.299f * r0.x + 0.587f * g0.x + 0.114f * b0.x) * 255.0f);
            unsigned int b_ = (unsigned int)rintf((0.299f * r0.y + 0.587f * g0.y + 0.114f * b0.y) * 255.0f);
            unsigned int c = (unsigned int)rintf((0.299f * r0.z + 0.587f * g0.z + 0.114f * b0.z) * 255.0f);
            unsigned int d = (unsigned int)rintf((0.299f * r0.w + 0.587f * g0.w + 0.114f * b0.w) * 255.0f);
            v0 = a | (b_ << 8) | (c << 16) | (d << 24);
        }
        {
            unsigned int a = (unsigned int)rintf((0.299f * r1.x + 0.587f * g1.x + 0.114f * b1.x) * 255.0f);
            unsigned int b_ = (unsigned int)rintf((0.299f * r1.y + 0.587f * g1.y + 0.114f * b1.y) * 255.0f);
            unsigned int c = (unsigned int)rintf((0.299f * r1.z + 0.587f * g1.z + 0.114f * b1.z) * 255.0f);
            unsigned int d = (unsigned int)rintf((0.299f * r1.w + 0.587f * g1.w + 0.114f * b1.w) * 255.0f);
            v1 = a | (b_ << 8) | (c << 16) | (d << 24);
        }
        y8[idx] = make_uint2(v0, v1);
    } else {
        int i = idx - gtotal;
        if (i < NGAM) {
            float g = (float)i * 0.001f + 0.2f;
            float l1 = lgammaf(1.0f / g);
            float l2 = lgammaf(2.0f / g);
            float l3 = lgammaf(3.0f / g);
            rg[i] = expf(2.0f * l2 - l1 - l3);
            rt[i] = expf(0.5f * (l1 - l3));
            mf[i] = expf(l2 - l1);
        }
    }
}

// ---------------- MSCN body (register-blocked separable 7-tap), templated source type,
// fp16 output (storage only; all arithmetic f32).
struct MscnS {
    float tile[38][40];
    float h1s[38][36];
    float h2s[38][36];
    float gw1[8];
};
// yt stored fp16 (storage only) -> ResizeS 19,296B: ms_rs smem-union < 20KB -> 8 blocks/CU
struct ResizeS {
    __half yt[70][72];
    float  vv[32][72];
};

template <typename TIN>
__device__ __forceinline__ void mscn_body(const TIN* __restrict__ src,
                                          __half* __restrict__ out, int H, int W,
                                          int ox0, int oy0, int b,
                                          int tx, int ty, int tid, MscnS& S) {
    if (tid < 7) {
        double s = 7.0 / 6.0;
        double sum = 0.0;
        #pragma unroll
        for (int k = 0; k < 7; k++) sum += exp(-(double)((k - 3) * (k - 3)) / (2.0 * s * s));
        double e = exp(-(double)((tid - 3) * (tid - 3)) / (2.0 * s * s));
        S.gw1[tid] = (float)(e / sum);
    }

    const TIN* p = src + (size_t)b * H * W;
    for (int t = tid; t < 38 * 38; t += 256) {
        int r = t / 38, c = t % 38;
        int gr = oy0 - 3 + r; gr = gr < 0 ? 0 : (gr >= H ? H - 1 : gr);
        int gc = ox0 - 3 + c; gc = gc < 0 ? 0 : (gc >= W ? W - 1 : gc);
        S.tile[r][c] = ldf(&p[(size_t)gr * W + gc]);
    }
    __syncthreads();

    for (int t = tid; t < 38 * 8; t += 256) {
        int r = t / 8, c0 = (t % 8) * 4;
        float4 f0 = *(const float4*)&S.tile[r][c0];
        float4 f1 = *(const float4*)&S.tile[r][c0 + 4];
        float2 f2 = *(const float2*)&S.tile[r][c0 + 8];
        float v[10] = {f0.x, f0.y, f0.z, f0.w, f1.x, f1.y, f1.z, f1.w, f2.x, f2.y};
        float s1[4] = {0, 0, 0, 0}, s2[4] = {0, 0, 0, 0};
        #pragma unroll
        for (int k = 0; k < 7; k++) {
            float w = S.gw1[k];
            #pragma unroll
            for (int s = 0; s < 4; s++) {
                float vv = v[s + k];
                s1[s] += w * vv;
                s2[s] += w * vv * vv;
            }
        }
        *(float4*)&S.h1s[r][c0] = make_float4(s1[0], s1[1], s1[2], s1[3]);
        *(float4*)&S.h2s[r][c0] = make_float4(s2[0], s2[1], s2[2], s2[3]);
    }
    __syncthreads();

    int ly0 = ty * 4;
    float a1[10], a2[10];
    #pragma unroll
    for (int k = 0; k < 10; k++) { a1[k] = S.h1s[ly0 + k][tx]; a2[k] = S.h2s[ly0 + k][tx]; }
    __half* q = out + (size_t)b * H * W;
    #pragma unroll
    for (int s = 0; s < 4; s++) {
        int oy = oy0 + ly0 + s, ox = ox0 + tx;
        if (oy < H) {
            float m1 = 0.0f, m2 = 0.0f;
            #pragma unroll
            for (int k = 0; k < 7; k++) {
                float w = S.gw1[k];
                m1 += w * a1[s + k];
                m2 += w * a2[s + k];
            }
            float sig = sqrtf(fabsf(m2 - m1 * m1));
            q[(size_t)oy * W + ox] = __float2half((S.tile[ly0 + s + 3][tx + 3] - m1) / (sig + 1.0f));
        }
    }
}

__device__ const float RW8[8] = {-0.01171875f, -0.03515625f, 0.11328125f, 0.43359375f,
                                  0.43359375f,  0.11328125f, -0.03515625f, -0.01171875f};

__device__ __forceinline__ void resize_body(const unsigned char* __restrict__ y,
                                            __half* __restrict__ half,
                                            int j0, int i0, int b, int tid, ResizeS& S) {
    const unsigned char* py = y + (size_t)b * H1 * W1;
    int rbase = 2 * i0 - 3, cbase = 2 * j0 - 3;

    for (int t = tid; t < 70 * 70; t += 256) {
        int r = t / 70, c = t % 70;
        int gr = reflect_idx(rbase + r, H1);
        int gc = reflect_idx(cbase + c, W1);
        S.yt[r][c] = __float2half((float)py[(size_t)gr * W1 + gc] / 255.0f);
    }
    __syncthreads();

    for (int t = tid; t < 32 * 70; t += 256) {
        int i = t / 70, c = t % 70;
        float acc = 0.0f;
        #pragma unroll
        for (int p = 0; p < 8; p++) acc += RW8[p] * __half2float(S.yt[2 * i + p][c]);
        S.vv[i][c] = acc;
    }
    __syncthreads();

    __half* ph = half + (size_t)b * H2 * W2;
    for (int t = tid; t < 1024; t += 256) {
        int i = t >> 5, j = t & 31;
        int oy = i0 + i, ox = j0 + j;
        if (oy < H2 && ox < W2) {
            float acc = 0.0f;
            #pragma unroll
            for (int p = 0; p < 8; p++) acc += RW8[p] * S.vv[i][2 * j + p];
            ph[(size_t)oy * W2 + ox] = __float2half(acc * 255.0f);
        }
    }
}

// merged mscn1 + resize (both consume uchar y, independent of each other)
__global__ __launch_bounds__(256) void k_ms_rs(const unsigned char* __restrict__ y,
                                               __half* __restrict__ nrm,
                                               __half* __restrict__ half) {
    __shared__ __align__(16) char smem[sizeof(ResizeS) > sizeof(MscnS) ? sizeof(ResizeS)
                                                                       : sizeof(MscnS)];
    int bid = blockIdx.x;
    int tid = threadIdx.x;
    int tx = tid & 31, ty = tid >> 5;
    if (bid < MS_NB) {
        int bx = bid % MS_BX;
        int t  = bid / MS_BX;
        int by = t % MS_BY;
        int b  = t / MS_BY;
        mscn_body<unsigned char>(y, nrm, H1, W1, bx * 32, by * 32, b, tx, ty, tid,
                                 *reinterpret_cast<MscnS*>(smem));
    } else {
        int rid = bid - MS_NB;
        int jx = rid % RS_BX;
        int t  = rid / RS_BX;
        int iy = t % RS_BY;
        int b  = t / RS_BY;
        resize_body(y, half, jx * 32, iy * 32, b, tid,
                    *reinterpret_cast<ResizeS*>(smem));
    }
}

// ---------------- FEATS phase A body: per-slice partial stats over fp16 norm
// (converted to f32 on load; all accumulation f32 — identical expressions).
template <int COLS, int TPR, int NT>
__device__ __forceinline__ void fpart_body(const __half* __restrict__ p, int W,
                                           int row0, int BSfull, int tid,
                                           float* __restrict__ outp) {
    constexpr int SPAN = 12, CW = 4, NCH = 3;
    constexpr int NW = NT / 64;
    __shared__ float wls[NW][25];
    if (tid < NT) {
        int lane = tid & 63, wv = tid >> 6;
        int li = tid / TPR;
        int c0 = (tid % TPR) * SPAN;
        int gi = row0 + li;
        int gim = (gi == 0) ? BSfull - 1 : gi - 1;
        const __half* rowcp = p + (size_t)gi * W;
        const __half* rowmp = p + (size_t)gim * W;

        float c2 = __half2float(rowcp[c0 == 0 ? COLS - 1 : c0 - 1]);
        float m2 = __half2float(rowmp[c0 == 0 ? COLS - 1 : c0 - 1]);
        float mrightE = __half2float(rowmp[c0 + SPAN == COLS ? 0 : c0 + SPAN]);

        float sn[5] = {0, 0, 0, 0, 0}, s2[5] = {0, 0, 0, 0, 0}, sa[5] = {0, 0, 0, 0, 0};
        int cneg[5] = {0, 0, 0, 0, 0}, cnz[5] = {0, 0, 0, 0, 0};

        auto PROC = [&](float v0, float cl, float up, float ul, float ur) {
            float v[5] = {v0, v0 * cl, v0 * up, v0 * ul, v0 * ur};
            #pragma unroll
            for (int s = 0; s < 5; s++) {
                float vv = v[s];
                float t = fminf(vv, 0.0f);
                sn[s] += t * t;
                s2[s] += vv * vv;
                sa[s] += fabsf(vv);
                cneg[s] += (int)__popcll(__ballot(vv < 0.0f));
                cnz[s]  += (int)__popcll(__ballot(vv != 0.0f));
            }
        };

        float c1 = 0.0f, m1 = 0.0f;
        #pragma unroll
        for (int j = 0; j < NCH; j++) {
            float cc[CW], mm[CW];
            {
                __half2 u0 = *(const __half2*)(rowcp + c0 + j * CW);
                __half2 u1 = *(const __half2*)(rowcp + c0 + j * CW + 2);
                float2 f0 = __half22float2(u0), f1 = __half22float2(u1);
                cc[0] = f0.x; cc[1] = f0.y; cc[2] = f1.x; cc[3] = f1.y;
            }
            #pragma unroll
            for (int k = 0; k < CW; k++) mm[k] = __shfl_up(cc[k], TPR, 64);
            if (lane < TPR) {
                __half2 u0 = *(const __half2*)(rowmp + c0 + j * CW);
                __half2 u1 = *(const __half2*)(rowmp + c0 + j * CW + 2);
                float2 f0 = __half22float2(u0), f1 = __half22float2(u1);
                mm[0] = f0.x; mm[1] = f0.y; mm[2] = f1.x; mm[3] = f1.y;
            }
            #pragma unroll
            for (int k = 0; k < CW; k++) {
                if (j == 0 && k == 0) { c1 = cc[0]; m1 = mm[0]; }
                else {
                    PROC(c1, c2, m1, m2, mm[k]);
                    c2 = c1; m2 = m1; c1 = cc[k]; m1 = mm[k];
                }
            }
        }
        PROC(c1, c2, m1, m2, mrightE);

        #pragma unroll
        for (int s = 0; s < 5; s++) {
            float vals[3] = {sn[s], s2[s], sa[s]};
            const int rows3[3] = {0, 1, 4};
            #pragma unroll
            for (int m = 0; m < 3; m++) {
                float v = vals[m];
                #pragma unroll
                for (int off = 32; off > 0; off >>= 1) v += __shfl_down(v, off, 64);
                if (lane == 0) wls[wv][s * 5 + rows3[m]] = v;
            }
            if (lane == 0) {
                wls[wv][s * 5 + 2] = (float)cneg[s];
                wls[wv][s * 5 + 3] = (float)cnz[s];
            }
        }
    }
    __syncthreads();
    if (tid < 25) {
        float s = 0.0f;
        #pragma unroll
        for (int w = 0; w < NW; w++) s += wls[w][tid];
        outp[tid] = s;
    }
}

// finalize: ss[25] -> 18 features
__device__ __forceinline__ void finalize_feats(int tid, int BS, const float* ss,
                                               float* srn, float* sls, float* srs,
                                               const float* __restrict__ rgam,
                                               const float* __restrict__ ratio_t,
                                               const float* __restrict__ meanfac_t,
                                               float* __restrict__ fp) {
    if (tid < 5) {
        int s = tid;
        float SN  = ss[s * 5 + 0];
        float S2  = ss[s * 5 + 1];
        float CN  = ss[s * 5 + 2];
        float CNZ = ss[s * 5 + 3];
        float SA  = ss[s * 5 + 4];
        float SP = S2 - SN;
        float CP = CNZ - CN;
        float ls = sqrtf(SN / CN);
        float rs = sqrtf(SP / CP);
        float gh = ls / rs;
        float Nn = (float)(BS * BS);
        float am = SA / Nn;
        float rhat = (am * am) / (S2 / Nn);
        float g2 = gh * gh;
        float rn = rhat * (g2 * gh + 1.0f) * (gh + 1.0f) / ((g2 + 1.0f) * (g2 + 1.0f));
        srn[s] = rn; sls[s] = ls; srs[s] = rs;
    }
    __syncthreads();
    if (tid < 64) {
        int lane = tid;
        for (int s = 0; s < 5; s++) {
            float rn = srn[s];
            int lo = -1, hi = NGAM;
            while (hi - lo > 1) {
                int n = hi - lo - 1;
                int stride = n / 65 + 1;
                int pi = lo + (lane + 1) * stride;
                bool valid = pi < hi;
                float v = valid ? rgam[pi] : 0.0f;
                unsigned long long blw = __ballot(valid && (v < rn));
                int k = __popcll(blw);
                int oldlo = lo;
                lo = oldlo + k * stride;
                int cand = oldlo + (k + 1) * stride;
                if (cand < hi) hi = cand;
            }
            int lb = hi;
            int ix;
            if (lb <= 0) ix = 0;
            else if (lb >= NGAM) ix = NGAM - 1;
            else {
                float dl = rgam[lb - 1] - rn, dr = rgam[lb] - rn;
                ix = (dl * dl <= dr * dr) ? lb - 1 : lb;
            }
            if (lane == 0) {
                float a = (float)ix * 0.001f + 0.2f;
                float ratio = ratio_t[ix];
                float bl = sls[s] * ratio;
                float br = srs[s] * ratio;
                if (s == 0) {
                    fp[0] = a; fp[1] = 0.5f * (bl + br);
                } else {
                    float mn = (br - bl) * meanfac_t[ix];
                    int base = 2 + (s - 1) * 4;
                    fp[base] = a; fp[base + 1] = mn; fp[base + 2] = bl; fp[base + 3] = br;
                }
            }
        }
    }
}

// ---------------- merged: fpart scale-1 (2640 blocks, 32-row slices, all 256 threads
// active) + mscn2 (2040 blocks)
__global__ __launch_bounds__(256) void k_mscn2_fpart1(const __half* __restrict__ nrm,
                                                      const __half* __restrict__ half,
                                                      __half* __restrict__ nrm2,
                                                      float* __restrict__ part) {
    __shared__ __align__(16) char smem[sizeof(MscnS)];
    int bid = blockIdx.x, tid = threadIdx.x;
    if (bid < NPART1) {
        int g = bid / NSL1, sl = bid % NSL1;
        int b = g / NBLK, r = g % NBLK;
        const __half* p = nrm + (size_t)b * H1 * W1 + (size_t)(r / NBW * 96) * W1
                        + (size_t)(r % NBW) * 96;
        fpart_body<96, 8, 256>(p, W1, sl * 32, 96, tid, part + (size_t)bid * 25);
    } else {
        int rid = bid - NPART1;
        int jx = rid % RS_BX;
        int t  = rid / RS_BX;
        int iy = t % RS_BY;
        int b  = t / RS_BY;
        mscn_body<__half>(half, nrm2, H2, W2, jx * 32, iy * 32, b,
                          tid & 31, tid >> 5, tid, *reinterpret_cast<MscnS*>(smem));
    }
}

// ---------------- merged: fpart scale-2 with INTRA-BLOCK finalize (880) + ffinal scale-1 (880)
__global__ __launch_bounds__(192) void k_fpart2_ffinal1(const __half* __restrict__ nrm2,
                                                        const float* __restrict__ part,
                                                        const float* __restrict__ rgam,
                                                        const float* __restrict__ ratio_t,
                                                        const float* __restrict__ meanfac_t,
                                                        float* __restrict__ feats) {
    __shared__ float ss[25];
    __shared__ float srn[5], sls[5], srs[5];
    int bid = blockIdx.x, tid = threadIdx.x;
    if (bid < NB * NBLK) {
        int g = bid;
        int b = g / NBLK, r = g % NBLK;
        const __half* p = nrm2 + (size_t)b * H2 * W2 + (size_t)(r / NBW * 48) * W2
                        + (size_t)(r % NBW) * 48;
        fpart_body<48, 4, 192>(p, W2, 0, 48, tid, ss);
        __syncthreads();
        finalize_feats(tid, 48, ss, srn, sls, srs, rgam, ratio_t, meanfac_t,
                       feats + (size_t)g * NF + 18);
    } else {
        int g = bid - NB * NBLK;
        if (tid < 25) {
            float s = 0.0f;
            #pragma unroll
            for (int sl = 0; sl < NSL1; sl++)
                s += part[(size_t)(g * NSL1 + sl) * 25 + tid];
            ss[tid] = s;
        }
        __syncthreads();
        finalize_feats(tid, 96, ss, srn, sls, srs, rgam, ratio_t, meanfac_t,
                       feats + (size_t)g * NF + 0);
    }
}

// ---------------- per-batch stats: cov via transposed dist + 3x3 register tiles,
// then no-pivot Gauss-Jordan (M is SPD), f32 throughout.
__global__ __launch_bounds__(256) void k_stats(const float* __restrict__ feats,
                                               const float* __restrict__ mu_pris,
                                               const float* __restrict__ cov_pris,
                                               float* __restrict__ out) {
    __shared__ float dist[NBLK * NF];
    __shared__ __align__(16) float distT[NF][228];
    __shared__ float mu[NF];
    __shared__ float M[NF][NF + 1];
    __shared__ float facs[NF];
    __shared__ float dd[NF];

    int b = blockIdx.x, tid = threadIdx.x;
    for (int t = tid; t < NBLK * NF; t += 256) dist[t] = feats[(size_t)b * NBLK * NF + t];
    __syncthreads();
    if (tid < NF) {
        float s = 0.0f;
        for (int n = 0; n < NBLK; n++) s += dist[n * NF + tid];
        mu[tid] = s / (float)NBLK;
    }
    __syncthreads();
    for (int t = tid; t < NF * NBLK; t += 256) {
        int f = t / NBLK, n = t % NBLK;
        distT[f][n] = dist[n * NF + f] - mu[f];
    }
    __syncthreads();

    if (tid < 144) {
        int f0 = (tid / 12) * 3, g0 = (tid % 12) * 3;
        float acc[3][3] = {{0,0,0},{0,0,0},{0,0,0}};
        for (int n = 0; n < NBLK; n += 4) {
            float4 A[3], B[3];
            #pragma unroll
            for (int i = 0; i < 3; i++) A[i] = *(const float4*)&distT[f0 + i][n];
            #pragma unroll
            for (int j = 0; j < 3; j++) B[j] = *(const float4*)&distT[g0 + j][n];
            #pragma unroll
            for (int i = 0; i < 3; i++)
                #pragma unroll
                for (int j = 0; j < 3; j++)
                    acc[i][j] += A[i].x * B[j].x + A[i].y * B[j].y
                               + A[i].z * B[j].z + A[i].w * B[j].w;
        }
        const float* cp = cov_pris + (size_t)b * NF * NF;
        #pragma unroll
        for (int i = 0; i < 3; i++)
            #pragma unroll
            for (int j = 0; j < 3; j++) {
                int f = f0 + i, gg = g0 + j;
                M[f][gg] = (cp[f * NF + gg] + acc[i][j] / (float)(NBLK - 1)) * 0.5f;
            }
    }
    if (tid < NF) {
        float d = mu_pris[b * NF + tid] - mu[tid];
        dd[tid] = d;
        M[tid][NF] = d;
    }
    __syncthreads();

    for (int k = 0; k < NF; k++) {
        if (tid < NF && tid != k) facs[tid] = M[tid][k] / M[k][k];
        __syncthreads();
        for (int t = tid; t < NF * (NF + 1); t += 256) {
            int i = t / (NF + 1), j = t % (NF + 1);
            if (i != k && j > k) M[i][j] -= facs[i] * M[k][j];
        }
        __syncthreads();
    }

    if (tid < 64) {
        double c = (tid < NF) ? (double)dd[tid] * ((double)M[tid][NF] / (double)M[tid][tid]) : 0.0;
        #pragma unroll
        for (int off = 32; off > 0; off >>= 1) c += __shfl_down(c, off, 64);
        if (tid == 0) out[b] = (float)sqrt(c);
    }
}

extern "C" void kernel_launch(void* const* d_in, const int* in_sizes, int n_in,
                              void* d_out, int out_size, void* d_ws, size_t ws_size,
                              hipStream_t stream) {
    const float* x        = (const float*)d_in[0];
    const float* mu_pris  = (const float*)d_in[1];
    const float* cov_pris = (const float*)d_in[2];
    float* out = (float*)d_out;

    char* base = (char*)d_ws;
    unsigned char* y8 = (unsigned char*)base;                       // 8,110,080 B
    __half* nrm  = (__half*)(base + 8110080);                       // 16,220,160 B
    __half* half = (__half*)(base + 8110080 + 16220160);            // 4,055,040 B
    __half* nrm2 = half + (size_t)NB * H2 * W2;                     // 4,055,040 B
    float* rgam  = (float*)((char*)nrm2 + (size_t)NB * H2 * W2 * 2);
    float* ratio = rgam + NGAM;
    float* mfac  = ratio + NGAM;
    float* feats = mfac + NGAM;                                     // NB*220*36
    float* part  = feats + (size_t)NB * NBLK * NF;                  // 2640*25

    const int NGB8 = NB * H1 * (W1 / 8);
    k_gray_rgam<<<(NGB8 + NGAM + 255) / 256, 256, 0, stream>>>(
        (const float4*)x, (uint2*)y8, rgam, ratio, mfac);

    k_ms_rs<<<MS_NB + RS_NB, 256, 0, stream>>>(y8, nrm, half);

    k_mscn2_fpart1<<<NPART1 + RS_NB, 256, 0, stream>>>(nrm, half, nrm2, part);

    k_fpart2_ffinal1<<<2 * NB * NBLK, 192, 0, stream>>>(nrm2, part, rgam, ratio, mfac, feats);

    k_stats<<<NB, 256, 0, stream>>>(feats, mu_pris, cov_pris, out);
}

// Round 22
// 148.467 us; speedup vs baseline: 2.2648x; 1.0016x over previous
//
#include <hip/hip_runtime.h>
#include <hip/hip_fp16.h>
#include <math.h>

#define NB   4
#define H1   1056
#define W1   1920
#define H2   528
#define W2   960
#define NBLK 220    // 11*20 blocks per image, both scales
#define NBW  20
#define NF   36
#define NGAM 9801
#define NSL1 3      // row-slices per 96-block (32 rows each -> 256 threads exactly)
#define NPART1 (NB * NBLK * NSL1)               // 2640 scale-1 slice partials

#define MS_BX (W1 / 32)            // 60
#define MS_BY (H1 / 32)            // 33
#define MS_NB (MS_BX * MS_BY * NB) // 7920
#define RS_BX (W2 / 32)            // 30
#define RS_BY ((H2 + 31) / 32)     // 17
#define RS_NB (RS_BX * RS_BY * NB) // 2040

__device__ __forceinline__ int reflect_idx(int i, int n) {
    if (i < 0) return -i - 1;
    if (i >= n) return 2 * n - i - 1;
    return i;
}

__device__ __forceinline__ float ldf(const unsigned char* p) { return (float)*p; }
__device__ __forceinline__ float ldf(const __half* p)        { return __half2float(*p); }

// ---------------- gray (8 px/thread, uchar8 output) + R_GAM tables in one launch.
// y values are rintf() results in [0,255] -> uchar roundtrip is bitwise exact.
__global__ void k_gray_rgam(const float4* __restrict__ x, uint2* __restrict__ y8,
                            float* __restrict__ rg, float* __restrict__ rt,
                            float* __restrict__ mf) {
    const int W8 = W1 / 8;                 // 240
    const int W4 = W1 / 4;                 // 480
    const int gtotal = NB * H1 * W8;
    int idx = blockIdx.x * 256 + threadIdx.x;
    if (idx < gtotal) {
        int w8 = idx % W8;
        int t  = idx / W8;
        int h  = t % H1;
        int b  = t / H1;
        size_t base = ((size_t)(b * 3) * 1080 + h) * W4 + w8 * 2;
        float4 r0 = x[base],                     r1 = x[base + 1];
        float4 g0 = x[base + (size_t)1080 * W4], g1 = x[base + (size_t)1080 * W4 + 1];
        float4 b0 = x[base + 2 * (size_t)1080 * W4], b1 = x[base + 2 * (size_t)1080 * W4 + 1];
        unsigned int v0, v1;
        {
            unsigned int a = (unsigned int)rintf((0.299f * r0.x + 0.587f * g0.x + 0.114f * b0.x) * 255.0f);
            unsigned int b_ = (unsigned int)rintf((0.299f * r0.y + 0.587f * g0.y + 0.114f * b0.y) * 255.0f);
            unsigned int c = (unsigned int)rintf((0.299f * r0.z + 0.587f * g0.z + 0.114f * b0.z) * 255.0f);
            unsigned int d = (unsigned int)rintf((0.299f * r0.w + 0.587f * g0.w + 0.114f * b0.w) * 255.0f);
            v0 = a | (b_ << 8) | (c << 16) | (d << 24);
        }
        {
            unsigned int a = (unsigned int)rintf((0.299f * r1.x + 0.587f * g1.x + 0.114f * b1.x) * 255.0f);
            unsigned int b_ = (unsigned int)rintf((0.299f * r1.y + 0.587f * g1.y + 0.114f * b1.y) * 255.0f);
            unsigned int c = (unsigned int)rintf((0.299f * r1.z + 0.587f * g1.z + 0.114f * b1.z) * 255.0f);
            unsigned int d = (unsigned int)rintf((0.299f * r1.w + 0.587f * g1.w + 0.114f * b1.w) * 255.0f);
            v1 = a | (b_ << 8) | (c << 16) | (d << 24);
        }
        y8[idx] = make_uint2(v0, v1);
    } else {
        int i = idx - gtotal;
        if (i < NGAM) {
            float g = (float)i * 0.001f + 0.2f;
            float l1 = lgammaf(1.0f / g);
            float l2 = lgammaf(2.0f / g);
            float l3 = lgammaf(3.0f / g);
            rg[i] = expf(2.0f * l2 - l1 - l3);
            rt[i] = expf(0.5f * (l1 - l3));
            mf[i] = expf(l2 - l1);
        }
    }
}

// ---------------- MSCN body (register-blocked separable 7-tap), templated source type,
// fp16 output (storage only; all arithmetic f32).
struct MscnS {
    float tile[38][40];
    float h1s[38][36];
    float h2s[38][36];
    float gw1[8];
};
// yt stored fp16 (storage only) -> ResizeS 19,296B: ms_rs smem-union < 20KB -> 8 blocks/CU
struct ResizeS {
    __half yt[70][72];
    float  vv[32][72];
};

template <typename TIN>
__device__ __forceinline__ void mscn_body(const TIN* __restrict__ src,
                                          __half* __restrict__ out, int H, int W,
                                          int ox0, int oy0, int b,
                                          int tx, int ty, int tid, MscnS& S) {
    if (tid < 7) {
        double s = 7.0 / 6.0;
        double sum = 0.0;
        #pragma unroll
        for (int k = 0; k < 7; k++) sum += exp(-(double)((k - 3) * (k - 3)) / (2.0 * s * s));
        double e = exp(-(double)((tid - 3) * (tid - 3)) / (2.0 * s * s));
        S.gw1[tid] = (float)(e / sum);
    }

    const TIN* p = src + (size_t)b * H * W;
    for (int t = tid; t < 38 * 38; t += 256) {
        int r = t / 38, c = t % 38;
        int gr = oy0 - 3 + r; gr = gr < 0 ? 0 : (gr >= H ? H - 1 : gr);
        int gc = ox0 - 3 + c; gc = gc < 0 ? 0 : (gc >= W ? W - 1 : gc);
        S.tile[r][c] = ldf(&p[(size_t)gr * W + gc]);
    }
    __syncthreads();

    for (int t = tid; t < 38 * 8; t += 256) {
        int r = t / 8, c0 = (t % 8) * 4;
        float4 f0 = *(const float4*)&S.tile[r][c0];
        float4 f1 = *(const float4*)&S.tile[r][c0 + 4];
        float2 f2 = *(const float2*)&S.tile[r][c0 + 8];
        float v[10] = {f0.x, f0.y, f0.z, f0.w, f1.x, f1.y, f1.z, f1.w, f2.x, f2.y};
        float s1[4] = {0, 0, 0, 0}, s2[4] = {0, 0, 0, 0};
        #pragma unroll
        for (int k = 0; k < 7; k++) {
            float w = S.gw1[k];
            #pragma unroll
            for (int s = 0; s < 4; s++) {
                float vv = v[s + k];
                s1[s] += w * vv;
                s2[s] += w * vv * vv;
            }
        }
        *(float4*)&S.h1s[r][c0] = make_float4(s1[0], s1[1], s1[2], s1[3]);
        *(float4*)&S.h2s[r][c0] = make_float4(s2[0], s2[1], s2[2], s2[3]);
    }
    __syncthreads();

    int ly0 = ty * 4;
    float a1[10], a2[10];
    #pragma unroll
    for (int k = 0; k < 10; k++) { a1[k] = S.h1s[ly0 + k][tx]; a2[k] = S.h2s[ly0 + k][tx]; }
    __half* q = out + (size_t)b * H * W;
    #pragma unroll
    for (int s = 0; s < 4; s++) {
        int oy = oy0 + ly0 + s, ox = ox0 + tx;
        if (oy < H) {
            float m1 = 0.0f, m2 = 0.0f;
            #pragma unroll
            for (int k = 0; k < 7; k++) {
                float w = S.gw1[k];
                m1 += w * a1[s + k];
                m2 += w * a2[s + k];
            }
            float sig = sqrtf(fabsf(m2 - m1 * m1));
            q[(size_t)oy * W + ox] = __float2half((S.tile[ly0 + s + 3][tx + 3] - m1) / (sig + 1.0f));
        }
    }
}

__device__ const float RW8[8] = {-0.01171875f, -0.03515625f, 0.11328125f, 0.43359375f,
                                  0.43359375f,  0.11328125f, -0.03515625f, -0.01171875f};

__device__ __forceinline__ void resize_body(const unsigned char* __restrict__ y,
                                            __half* __restrict__ half,
                                            int j0, int i0, int b, int tid, ResizeS& S) {
    const unsigned char* py = y + (size_t)b * H1 * W1;
    int rbase = 2 * i0 - 3, cbase = 2 * j0 - 3;

    for (int t = tid; t < 70 * 70; t += 256) {
        int r = t / 70, c = t % 70;
        int gr = reflect_idx(rbase + r, H1);
        int gc = reflect_idx(cbase + c, W1);
        S.yt[r][c] = __float2half((float)py[(size_t)gr * W1 + gc] / 255.0f);
    }
    __syncthreads();

    for (int t = tid; t < 32 * 70; t += 256) {
        int i = t / 70, c = t % 70;
        float acc = 0.0f;
        #pragma unroll
        for (int p = 0; p < 8; p++) acc += RW8[p] * __half2float(S.yt[2 * i + p][c]);
        S.vv[i][c] = acc;
    }
    __syncthreads();

    __half* ph = half + (size_t)b * H2 * W2;
    for (int t = tid; t < 1024; t += 256) {
        int i = t >> 5, j = t & 31;
        int oy = i0 + i, ox = j0 + j;
        if (oy < H2 && ox < W2) {
            float acc = 0.0f;
            #pragma unroll
            for (int p = 0; p < 8; p++) acc += RW8[p] * S.vv[i][2 * j + p];
            ph[(size_t)oy * W2 + ox] = __float2half(acc * 255.0f);
        }
    }
}

// merged mscn1 + resize (both consume uchar y, independent of each other)
__global__ __launch_bounds__(256) void k_ms_rs(const unsigned char* __restrict__ y,
                                               __half* __restrict__ nrm,
                                               __half* __restrict__ half) {
    __shared__ __align__(16) char smem[sizeof(ResizeS) > sizeof(MscnS) ? sizeof(ResizeS)
                                                                       : sizeof(MscnS)];
    int bid = blockIdx.x;
    int tid = threadIdx.x;
    int tx = tid & 31, ty = tid >> 5;
    if (bid < MS_NB) {
        int bx = bid % MS_BX;
        int t  = bid / MS_BX;
        int by = t % MS_BY;
        int b  = t / MS_BY;
        mscn_body<unsigned char>(y, nrm, H1, W1, bx * 32, by * 32, b, tx, ty, tid,
                                 *reinterpret_cast<MscnS*>(smem));
    } else {
        int rid = bid - MS_NB;
        int jx = rid % RS_BX;
        int t  = rid / RS_BX;
        int iy = t % RS_BY;
        int b  = t / RS_BY;
        resize_body(y, half, jx * 32, iy * 32, b, tid,
                    *reinterpret_cast<ResizeS*>(smem));
    }
}

// ---------------- FEATS phase A body: per-slice partial stats over fp16 norm
// (converted to f32 on load; all accumulation f32 — identical expressions).
template <int COLS, int TPR, int NT>
__device__ __forceinline__ void fpart_body(const __half* __restrict__ p, int W,
                                           int row0, int BSfull, int tid,
                                           float* __restrict__ outp) {
    constexpr int SPAN = 12, CW = 4, NCH = 3;
    constexpr int NW = NT / 64;
    __shared__ float wls[NW][25];
    if (tid < NT) {
        int lane = tid & 63, wv = tid >> 6;
        int li = tid / TPR;
        int c0 = (tid % TPR) * SPAN;
        int gi = row0 + li;
        int gim = (gi == 0) ? BSfull - 1 : gi - 1;
        const __half* rowcp = p + (size_t)gi * W;
        const __half* rowmp = p + (size_t)gim * W;

        float c2 = __half2float(rowcp[c0 == 0 ? COLS - 1 : c0 - 1]);
        float m2 = __half2float(rowmp[c0 == 0 ? COLS - 1 : c0 - 1]);
        float mrightE = __half2float(rowmp[c0 + SPAN == COLS ? 0 : c0 + SPAN]);

        float sn[5] = {0, 0, 0, 0, 0}, s2[5] = {0, 0, 0, 0, 0}, sa[5] = {0, 0, 0, 0, 0};
        int cneg[5] = {0, 0, 0, 0, 0}, cnz[5] = {0, 0, 0, 0, 0};

        auto PROC = [&](float v0, float cl, float up, float ul, float ur) {
            float v[5] = {v0, v0 * cl, v0 * up, v0 * ul, v0 * ur};
            #pragma unroll
            for (int s = 0; s < 5; s++) {
                float vv = v[s];
                float t = fminf(vv, 0.0f);
                sn[s] += t * t;
                s2[s] += vv * vv;
                sa[s] += fabsf(vv);
                cneg[s] += (int)__popcll(__ballot(vv < 0.0f));
                cnz[s]  += (int)__popcll(__ballot(vv != 0.0f));
            }
        };

        float c1 = 0.0f, m1 = 0.0f;
        #pragma unroll
        for (int j = 0; j < NCH; j++) {
            float cc[CW], mm[CW];
            {
                __half2 u0 = *(const __half2*)(rowcp + c0 + j * CW);
                __half2 u1 = *(const __half2*)(rowcp + c0 + j * CW + 2);
                float2 f0 = __half22float2(u0), f1 = __half22float2(u1);
                cc[0] = f0.x; cc[1] = f0.y; cc[2] = f1.x; cc[3] = f1.y;
            }
            #pragma unroll
            for (int k = 0; k < CW; k++) mm[k] = __shfl_up(cc[k], TPR, 64);
            if (lane < TPR) {
                __half2 u0 = *(const __half2*)(rowmp + c0 + j * CW);
                __half2 u1 = *(const __half2*)(rowmp + c0 + j * CW + 2);
                float2 f0 = __half22float2(u0), f1 = __half22float2(u1);
                mm[0] = f0.x; mm[1] = f0.y; mm[2] = f1.x; mm[3] = f1.y;
            }
            #pragma unroll
            for (int k = 0; k < CW; k++) {
                if (j == 0 && k == 0) { c1 = cc[0]; m1 = mm[0]; }
                else {
                    PROC(c1, c2, m1, m2, mm[k]);
                    c2 = c1; m2 = m1; c1 = cc[k]; m1 = mm[k];
                }
            }
        }
        PROC(c1, c2, m1, m2, mrightE);

        #pragma unroll
        for (int s = 0; s < 5; s++) {
            float vals[3] = {sn[s], s2[s], sa[s]};
            const int rows3[3] = {0, 1, 4};
            #pragma unroll
            for (int m = 0; m < 3; m++) {
                float v = vals[m];
                #pragma unroll
                for (int off = 32; off > 0; off >>= 1) v += __shfl_down(v, off, 64);
                if (lane == 0) wls[wv][s * 5 + rows3[m]] = v;
            }
            if (lane == 0) {
                wls[wv][s * 5 + 2] = (float)cneg[s];
                wls[wv][s * 5 + 3] = (float)cnz[s];
            }
        }
    }
    __syncthreads();
    if (tid < 25) {
        float s = 0.0f;
        #pragma unroll
        for (int w = 0; w < NW; w++) s += wls[w][tid];
        outp[tid] = s;
    }
}

// finalize: ss[25] -> 18 features
__device__ __forceinline__ void finalize_feats(int tid, int BS, const float* ss,
                                               float* srn, float* sls, float* srs,
                                               const float* __restrict__ rgam,
                                               const float* __restrict__ ratio_t,
                                               const float* __restrict__ meanfac_t,
                                               float* __restrict__ fp) {
    if (tid < 5) {
        int s = tid;
        float SN  = ss[s * 5 + 0];
        float S2  = ss[s * 5 + 1];
        float CN  = ss[s * 5 + 2];
        float CNZ = ss[s * 5 + 3];
        float SA  = ss[s * 5 + 4];
        float SP = S2 - SN;
        float CP = CNZ - CN;
        float ls = sqrtf(SN / CN);
        float rs = sqrtf(SP / CP);
        float gh = ls / rs;
        float Nn = (float)(BS * BS);
        float am = SA / Nn;
        float rhat = (am * am) / (S2 / Nn);
        float g2 = gh * gh;
        float rn = rhat * (g2 * gh + 1.0f) * (gh + 1.0f) / ((g2 + 1.0f) * (g2 + 1.0f));
        srn[s] = rn; sls[s] = ls; srs[s] = rs;
    }
    __syncthreads();
    if (tid < 64) {
        int lane = tid;
        for (int s = 0; s < 5; s++) {
            float rn = srn[s];
            int lo = -1, hi = NGAM;
            while (hi - lo > 1) {
                int n = hi - lo - 1;
                int stride = n / 65 + 1;
                int pi = lo + (lane + 1) * stride;
                bool valid = pi < hi;
                float v = valid ? rgam[pi] : 0.0f;
                unsigned long long blw = __ballot(valid && (v < rn));
                int k = __popcll(blw);
                int oldlo = lo;
                lo = oldlo + k * stride;
                int cand = oldlo + (k + 1) * stride;
                if (cand < hi) hi = cand;
            }
            int lb = hi;
            int ix;
            if (lb <= 0) ix = 0;
            else if (lb >= NGAM) ix = NGAM - 1;
            else {
                float dl = rgam[lb - 1] - rn, dr = rgam[lb] - rn;
                ix = (dl * dl <= dr * dr) ? lb - 1 : lb;
            }
            if (lane == 0) {
                float a = (float)ix * 0.001f + 0.2f;
                float ratio = ratio_t[ix];
                float bl = sls[s] * ratio;
                float br = srs[s] * ratio;
                if (s == 0) {
                    fp[0] = a; fp[1] = 0.5f * (bl + br);
                } else {
                    float mn = (br - bl) * meanfac_t[ix];
                    int base = 2 + (s - 1) * 4;
                    fp[base] = a; fp[base + 1] = mn; fp[base + 2] = bl; fp[base + 3] = br;
                }
            }
        }
    }
}

// ---------------- merged: fpart scale-1 (2640 blocks, 32-row slices, all 256 threads
// active) + mscn2 (2040 blocks)
__global__ __launch_bounds__(256) void k_mscn2_fpart1(const __half* __restrict__ nrm,
                                                      const __half* __restrict__ half,
                                                      __half* __restrict__ nrm2,
                                                      float* __restrict__ part) {
    __shared__ __align__(16) char smem[sizeof(MscnS)];
    int bid = blockIdx.x, tid = threadIdx.x;
    if (bid < NPART1) {
        int g = bid / NSL1, sl = bid % NSL1;
        int b = g / NBLK, r = g % NBLK;
        const __half* p = nrm + (size_t)b * H1 * W1 + (size_t)(r / NBW * 96) * W1
                        + (size_t)(r % NBW) * 96;
        fpart_body<96, 8, 256>(p, W1, sl * 32, 96, tid, part + (size_t)bid * 25);
    } else {
        int rid = bid - NPART1;
        int jx = rid % RS_BX;
        int t  = rid / RS_BX;
        int iy = t % RS_BY;
        int b  = t / RS_BY;
        mscn_body<__half>(half, nrm2, H2, W2, jx * 32, iy * 32, b,
                          tid & 31, tid >> 5, tid, *reinterpret_cast<MscnS*>(smem));
    }
}

// ---------------- merged: fpart scale-2 with INTRA-BLOCK finalize (880) + ffinal scale-1 (880)
__global__ __launch_bounds__(192) void k_fpart2_ffinal1(const __half* __restrict__ nrm2,
                                                        const float* __restrict__ part,
                                                        const float* __restrict__ rgam,
                                                        const float* __restrict__ ratio_t,
                                                        const float* __restrict__ meanfac_t,
                                                        float* __restrict__ feats) {
    __shared__ float ss[25];
    __shared__ float srn[5], sls[5], srs[5];
    int bid = blockIdx.x, tid = threadIdx.x;
    if (bid < NB * NBLK) {
        int g = bid;
        int b = g / NBLK, r = g % NBLK;
        const __half* p = nrm2 + (size_t)b * H2 * W2 + (size_t)(r / NBW * 48) * W2
                        + (size_t)(r % NBW) * 48;
        fpart_body<48, 4, 192>(p, W2, 0, 48, tid, ss);
        __syncthreads();
        finalize_feats(tid, 48, ss, srn, sls, srs, rgam, ratio_t, meanfac_t,
                       feats + (size_t)g * NF + 18);
    } else {
        int g = bid - NB * NBLK;
        if (tid < 25) {
            float s = 0.0f;
            #pragma unroll
            for (int sl = 0; sl < NSL1; sl++)
                s += part[(size_t)(g * NSL1 + sl) * 25 + tid];
            ss[tid] = s;
        }
        __syncthreads();
        finalize_feats(tid, 96, ss, srn, sls, srs, rgam, ratio_t, meanfac_t,
                       feats + (size_t)g * NF + 0);
    }
}

// ---------------- per-batch stats: cov via transposed dist + 3x3 register tiles,
// then no-pivot Gauss-Jordan (M is SPD), f32 throughout.
__global__ __launch_bounds__(256) void k_stats(const float* __restrict__ feats,
                                               const float* __restrict__ mu_pris,
                                               const float* __restrict__ cov_pris,
                                               float* __restrict__ out) {
    __shared__ float dist[NBLK * NF];
    __shared__ __align__(16) float distT[NF][228];
    __shared__ float mu[NF];
    __shared__ float M[NF][NF + 1];
    __shared__ float facs[NF];
    __shared__ float dd[NF];

    int b = blockIdx.x, tid = threadIdx.x;
    for (int t = tid; t < NBLK * NF; t += 256) dist[t] = feats[(size_t)b * NBLK * NF + t];
    __syncthreads();
    if (tid < NF) {
        float s = 0.0f;
        for (int n = 0; n < NBLK; n++) s += dist[n * NF + tid];
        mu[tid] = s / (float)NBLK;
    }
    __syncthreads();
    for (int t = tid; t < NF * NBLK; t += 256) {
        int f = t / NBLK, n = t % NBLK;
        distT[f][n] = dist[n * NF + f] - mu[f];
    }
    __syncthreads();

    if (tid < 144) {
        int f0 = (tid / 12) * 3, g0 = (tid % 12) * 3;
        float acc[3][3] = {{0,0,0},{0,0,0},{0,0,0}};
        for (int n = 0; n < NBLK; n += 4) {
            float4 A[3], B[3];
            #pragma unroll
            for (int i = 0; i < 3; i++) A[i] = *(const float4*)&distT[f0 + i][n];
            #pragma unroll
            for (int j = 0; j < 3; j++) B[j] = *(const float4*)&distT[g0 + j][n];
            #pragma unroll
            for (int i = 0; i < 3; i++)
                #pragma unroll
                for (int j = 0; j < 3; j++)
                    acc[i][j] += A[i].x * B[j].x + A[i].y * B[j].y
                               + A[i].z * B[j].z + A[i].w * B[j].w;
        }
        const float* cp = cov_pris + (size_t)b * NF * NF;
        #pragma unroll
        for (int i = 0; i < 3; i++)
            #pragma unroll
            for (int j = 0; j < 3; j++) {
                int f = f0 + i, gg = g0 + j;
                M[f][gg] = (cp[f * NF + gg] + acc[i][j] / (float)(NBLK - 1)) * 0.5f;
            }
    }
    if (tid < NF) {
        float d = mu_pris[b * NF + tid] - mu[tid];
        dd[tid] = d;
        M[tid][NF] = d;
    }
    __syncthreads();

    for (int k = 0; k < NF; k++) {
        if (tid < NF && tid != k) facs[tid] = M[tid][k] / M[k][k];
        __syncthreads();
        for (int t = tid; t < NF * (NF + 1); t += 256) {
            int i = t / (NF + 1), j = t % (NF + 1);
            if (i != k && j > k) M[i][j] -= facs[i] * M[k][j];
        }
        __syncthreads();
    }

    if (tid < 64) {
        double c = (tid < NF) ? (double)dd[tid] * ((double)M[tid][NF] / (double)M[tid][tid]) : 0.0;
        #pragma unroll
        for (int off = 32; off > 0; off >>= 1) c += __shfl_down(c, off, 64);
        if (tid == 0) out[b] = (float)sqrt(c);
    }
}

extern "C" void kernel_launch(void* const* d_in, const int* in_sizes, int n_in,
                              void* d_out, int out_size, void* d_ws, size_t ws_size,
                              hipStream_t stream) {
    const float* x        = (const float*)d_in[0];
    const float* mu_pris  = (const float*)d_in[1];
    const float* cov_pris = (const float*)d_in[2];
    float* out = (float*)d_out;

    char* base = (char*)d_ws;
    unsigned char* y8 = (unsigned char*)base;                       // 8,110,080 B
    __half* nrm  = (__half*)(base + 8110080);                       // 16,220,160 B
    __half* half = (__half*)(base + 8110080 + 16220160);            // 4,055,040 B
    __half* nrm2 = half + (size_t)NB * H2 * W2;                     // 4,055,040 B
    float* rgam  = (float*)((char*)nrm2 + (size_t)NB * H2 * W2 * 2);
    float* ratio = rgam + NGAM;
    float* mfac  = ratio + NGAM;
    float* feats = mfac + NGAM;                                     // NB*220*36
    float* part  = feats + (size_t)NB * NBLK * NF;                  // 2640*25

    const int NGB8 = NB * H1 * (W1 / 8);
    k_gray_rgam<<<(NGB8 + NGAM + 255) / 256, 256, 0, stream>>>(
        (const float4*)x, (uint2*)y8, rgam, ratio, mfac);

    k_ms_rs<<<MS_NB + RS_NB, 256, 0, stream>>>(y8, nrm, half);

    k_mscn2_fpart1<<<NPART1 + RS_NB, 256, 0, stream>>>(nrm, half, nrm2, part);

    k_fpart2_ffinal1<<<2 * NB * NBLK, 192, 0, stream>>>(nrm2, part, rgam, ratio, mfac, feats);

    k_stats<<<NB, 256, 0, stream>>>(feats, mu_pris, cov_pris, out);
}